// Round 1
// baseline (14342.769 us; speedup 1.0000x reference)
//
#include <hip/hip_runtime.h>
#include <cmath>

#define D_MODEL 1024
#define N_HEADS 16
#define DKH     64
#define SEQ_T   1024
#define BATCH   2
#define VOCAB   32000
#define DFF_    4096
#define NLAYERS 8

typedef __bf16 bf16x8 __attribute__((ext_vector_type(8)));
typedef float  f32x4  __attribute__((ext_vector_type(4)));

__device__ __forceinline__ float gelu_f(float x) {
    return 0.5f * x * (1.0f + erff(x * 0.70710678118654752f));
}

// ---------------------------------------------------------------------------
// Embedding: h[b,t,:] = inp_emb[x[b,t],:] + pos_emb[t,:]
// ---------------------------------------------------------------------------
__global__ __launch_bounds__(256) void embed_kernel(
    const int* __restrict__ x, const float* __restrict__ inp_emb,
    const float* __restrict__ pos_emb, float* __restrict__ h)
{
    const int idx = blockIdx.x * 256 + threadIdx.x;      // over B*T*D
    const int bt  = idx >> 10;          // /D
    const int d   = idx & 1023;         // %D
    const int t   = bt & (SEQ_T - 1);
    const int tok = x[bt];
    h[idx] = inp_emb[(size_t)tok * D_MODEL + d] + pos_emb[(size_t)t * D_MODEL + d];
}

// ---------------------------------------------------------------------------
// LayerNorm over last dim (D=1024). One block (256 thr) per row.
// ---------------------------------------------------------------------------
__global__ __launch_bounds__(256) void layernorm_kernel(
    const float* __restrict__ x, const float* __restrict__ sc,
    const float* __restrict__ bi, float* __restrict__ o)
{
    const int row = blockIdx.x;
    const int tid = threadIdx.x;
    const int c   = tid * 4;
    const float4 v = *(const float4*)(x + (size_t)row * D_MODEL + c);
    float sum = v.x + v.y + v.z + v.w;
    float sq  = v.x * v.x + v.y * v.y + v.z * v.z + v.w * v.w;
    #pragma unroll
    for (int off = 32; off > 0; off >>= 1) {
        sum += __shfl_xor(sum, off);
        sq  += __shfl_xor(sq, off);
    }
    __shared__ float ssum[4], ssq[4];
    const int wave = tid >> 6, lane = tid & 63;
    if (lane == 0) { ssum[wave] = sum; ssq[wave] = sq; }
    __syncthreads();
    sum = ssum[0] + ssum[1] + ssum[2] + ssum[3];
    sq  = ssq[0]  + ssq[1]  + ssq[2]  + ssq[3];
    const float mu  = sum * (1.0f / D_MODEL);
    const float var = sq * (1.0f / D_MODEL) - mu * mu;
    const float rs  = rsqrtf(var + 1e-5f);
    const float4 s4 = *(const float4*)(sc + c);
    const float4 b4 = *(const float4*)(bi + c);
    float4 ov;
    ov.x = (v.x - mu) * rs * s4.x + b4.x;
    ov.y = (v.y - mu) * rs * s4.y + b4.y;
    ov.z = (v.z - mu) * rs * s4.z + b4.z;
    ov.w = (v.w - mu) * rs * s4.w + b4.w;
    *(float4*)(o + (size_t)row * D_MODEL + c) = ov;
}

// ---------------------------------------------------------------------------
// GEMM: C[M,N] = epilogue(A[M,K] @ W[K,N] + bias).  f32 in, bf16 MFMA, f32 out.
// EPI: 0 = bias only; 1 = bias + residual add; 2 = bias + exact GELU.
// Requires M%64==0, N%64==0, K%32==0 (true for all shapes here).
// Block: 256 thr (4 waves). Tile 64x64, BK=32. Wave w -> rows [w*16, w*16+16).
// ---------------------------------------------------------------------------
template <int EPI>
__global__ __launch_bounds__(256) void gemm_kernel(
    const float* __restrict__ A, const float* __restrict__ W,
    const float* __restrict__ bias, const float* __restrict__ res,
    float* __restrict__ C, int M, int N, int K)
{
    __shared__ __bf16 As[64][40];   // [row][k], +8 pad
    __shared__ __bf16 Bs[64][40];   // [col][k], +8 pad (transposed at stage)
    const int tid  = threadIdx.x;
    const int wave = tid >> 6;
    const int lane = tid & 63;
    const int bm   = blockIdx.y * 64;
    const int bn   = blockIdx.x * 64;

    f32x4 acc[4] = {};

    const int arow = tid >> 2;          // 0..63
    const int acol = (tid & 3) * 8;     // 0,8,16,24
    const int brow = tid >> 3;          // k 0..31
    const int bcol = (tid & 7) * 8;     // col 0..56

    const int r  = lane & 15;
    const int kb = lane >> 4;

    for (int k0 = 0; k0 < K; k0 += 32) {
        const float* ap = A + (size_t)(bm + arow) * K + k0 + acol;
        const float4 a0 = *(const float4*)ap;
        const float4 a1 = *(const float4*)(ap + 4);
        const float* wp = W + (size_t)(k0 + brow) * N + bn + bcol;
        const float4 w0 = *(const float4*)wp;
        const float4 w1 = *(const float4*)(wp + 4);
        As[arow][acol + 0] = (__bf16)a0.x;
        As[arow][acol + 1] = (__bf16)a0.y;
        As[arow][acol + 2] = (__bf16)a0.z;
        As[arow][acol + 3] = (__bf16)a0.w;
        As[arow][acol + 4] = (__bf16)a1.x;
        As[arow][acol + 5] = (__bf16)a1.y;
        As[arow][acol + 6] = (__bf16)a1.z;
        As[arow][acol + 7] = (__bf16)a1.w;
        Bs[bcol + 0][brow] = (__bf16)w0.x;
        Bs[bcol + 1][brow] = (__bf16)w0.y;
        Bs[bcol + 2][brow] = (__bf16)w0.z;
        Bs[bcol + 3][brow] = (__bf16)w0.w;
        Bs[bcol + 4][brow] = (__bf16)w1.x;
        Bs[bcol + 5][brow] = (__bf16)w1.y;
        Bs[bcol + 6][brow] = (__bf16)w1.z;
        Bs[bcol + 7][brow] = (__bf16)w1.w;
        __syncthreads();

        bf16x8 af;
        #pragma unroll
        for (int j = 0; j < 8; ++j) af[j] = As[wave * 16 + r][kb * 8 + j];
        #pragma unroll
        for (int n = 0; n < 4; ++n) {
            bf16x8 bfr;
            #pragma unroll
            for (int j = 0; j < 8; ++j) bfr[j] = Bs[n * 16 + r][kb * 8 + j];
            acc[n] = __builtin_amdgcn_mfma_f32_16x16x32_bf16(af, bfr, acc[n], 0, 0, 0);
        }
        __syncthreads();
    }

    #pragma unroll
    for (int n = 0; n < 4; ++n) {
        #pragma unroll
        for (int rg = 0; rg < 4; ++rg) {
            const int row = bm + wave * 16 + kb * 4 + rg;
            const int col = bn + n * 16 + r;
            float vv = acc[n][rg];
            if (bias) vv += bias[col];
            if (EPI == 1) vv += res[(size_t)row * N + col];
            if (EPI == 2) vv = gelu_f(vv);
            C[(size_t)row * N + col] = vv;
        }
    }
}

// ---------------------------------------------------------------------------
// Causal flash attention, f32. One wave per (b,h,t) query row; lane = head dim.
// q,k,v,y layout: [B,T,D] with column h*DKH+d.
// ---------------------------------------------------------------------------
__global__ __launch_bounds__(64) void attn_kernel(
    const float* __restrict__ q, const float* __restrict__ k,
    const float* __restrict__ v, float* __restrict__ y)
{
    const int lane = threadIdx.x;
    const int t    = blockIdx.x;
    const int bh   = blockIdx.y;
    const int b    = bh >> 4;
    const int h    = bh & 15;
    const size_t rowbase = (size_t)b * SEQ_T * D_MODEL + h * DKH + lane;
    const float qv = q[rowbase + (size_t)t * D_MODEL];
    float m = -INFINITY, l = 0.0f, acc = 0.0f;
    for (int ki = 0; ki <= t; ++ki) {
        const size_t off = rowbase + (size_t)ki * D_MODEL;
        float s = qv * k[off];
        #pragma unroll
        for (int sh = 32; sh > 0; sh >>= 1) s += __shfl_xor(s, sh);
        s *= 0.125f;  // 1/sqrt(64)
        const float mn   = fmaxf(m, s);
        const float p    = __expf(s - mn);
        const float corr = __expf(m - mn);
        l   = l * corr + p;
        acc = acc * corr + p * v[off];
        m = mn;
    }
    y[rowbase + (size_t)t * D_MODEL] = acc / l;
}

// ---------------------------------------------------------------------------
extern "C" void kernel_launch(void* const* d_in, const int* in_sizes, int n_in,
                              void* d_out, int out_size, void* d_ws, size_t ws_size,
                              hipStream_t stream)
{
    const int*   x       = (const int*)  d_in[0];
    const float* inp_emb = (const float*)d_in[1];
    const float* pos_emb = (const float*)d_in[2];
    const float* wq = (const float*)d_in[3];
    const float* bq = (const float*)d_in[4];
    const float* wk = (const float*)d_in[5];
    const float* bk = (const float*)d_in[6];
    const float* wv = (const float*)d_in[7];
    const float* bv = (const float*)d_in[8];
    const float* wo = (const float*)d_in[9];
    const float* bo = (const float*)d_in[10];
    const float* w1 = (const float*)d_in[11];
    const float* b1 = (const float*)d_in[12];
    const float* w2 = (const float*)d_in[13];
    const float* b2 = (const float*)d_in[14];
    const float* ln1_s = (const float*)d_in[15];
    const float* ln1_b = (const float*)d_in[16];
    const float* ln2_s = (const float*)d_in[17];
    const float* ln2_b = (const float*)d_in[18];
    const float* lno_s = (const float*)d_in[19];
    const float* lno_b = (const float*)d_in[20];
    const float* w_out = (const float*)d_in[21];

    const size_t NTOK = (size_t)BATCH * SEQ_T;   // 2048
    float* ws  = (float*)d_ws;
    float* h   = ws;
    float* xn  = h   + NTOK * D_MODEL;
    float* qb  = xn  + NTOK * D_MODEL;
    float* kb  = qb  + NTOK * D_MODEL;
    float* vb  = kb  + NTOK * D_MODEL;
    float* yb  = vb  + NTOK * D_MODEL;
    float* mid = yb  + NTOK * D_MODEL;           // NTOK * DFF_

    const int M = (int)NTOK;                     // 2048

    // h = embed
    embed_kernel<<<dim3((M * D_MODEL) / 256), 256, 0, stream>>>(x, inp_emb, pos_emb, h);

    for (int i = 0; i < NLAYERS; ++i) {
        const size_t wOff  = (size_t)i * D_MODEL * D_MODEL;
        const size_t w1Off = (size_t)i * D_MODEL * DFF_;
        const size_t w2Off = (size_t)i * DFF_ * D_MODEL;

        // xn = LN1(h)
        layernorm_kernel<<<dim3(M), 256, 0, stream>>>(h, ln1_s + i * D_MODEL, ln1_b + i * D_MODEL, xn);
        // q,k,v
        gemm_kernel<0><<<dim3(D_MODEL / 64, M / 64), 256, 0, stream>>>(
            xn, wq + wOff, bq + i * D_MODEL, nullptr, qb, M, D_MODEL, D_MODEL);
        gemm_kernel<0><<<dim3(D_MODEL / 64, M / 64), 256, 0, stream>>>(
            xn, wk + wOff, bk + i * D_MODEL, nullptr, kb, M, D_MODEL, D_MODEL);
        gemm_kernel<0><<<dim3(D_MODEL / 64, M / 64), 256, 0, stream>>>(
            xn, wv + wOff, bv + i * D_MODEL, nullptr, vb, M, D_MODEL, D_MODEL);
        // y = attention(q,k,v)
        attn_kernel<<<dim3(SEQ_T, BATCH * N_HEADS), 64, 0, stream>>>(qb, kb, vb, yb);
        // h = h + y @ wo + bo
        gemm_kernel<1><<<dim3(D_MODEL / 64, M / 64), 256, 0, stream>>>(
            yb, wo + wOff, bo + i * D_MODEL, h, h, M, D_MODEL, D_MODEL);
        // xn = LN2(h)
        layernorm_kernel<<<dim3(M), 256, 0, stream>>>(h, ln2_s + i * D_MODEL, ln2_b + i * D_MODEL, xn);
        // mid = gelu(xn @ w1 + b1)
        gemm_kernel<2><<<dim3(DFF_ / 64, M / 64), 256, 0, stream>>>(
            xn, w1 + w1Off, b1 + i * DFF_, nullptr, mid, M, DFF_, D_MODEL);
        // h = h + mid @ w2 + b2
        gemm_kernel<1><<<dim3(D_MODEL / 64, M / 64), 256, 0, stream>>>(
            mid, w2 + w2Off, b2 + i * D_MODEL, h, h, M, D_MODEL, DFF_);
    }

    // xn = LN_out(h); logits = xn @ w_out
    layernorm_kernel<<<dim3(M), 256, 0, stream>>>(h, lno_s, lno_b, xn);
    gemm_kernel<0><<<dim3(VOCAB / 64, M / 64), 256, 0, stream>>>(
        xn, w_out, nullptr, nullptr, (float*)d_out, M, VOCAB, D_MODEL);
}

// Round 2
// 4420.336 us; speedup vs baseline: 3.2447x; 3.2447x over previous
//
#include <hip/hip_runtime.h>
#include <cmath>

#define D_MODEL 1024
#define N_HEADS 16
#define DKH     64
#define SEQ_T   1024
#define BATCH   2
#define VOCAB   32000
#define DFF_    4096
#define NLAYERS 8

typedef __bf16 bf16x8 __attribute__((ext_vector_type(8)));
typedef float  f32x4  __attribute__((ext_vector_type(4)));

__device__ __forceinline__ float gelu_f(float x) {
    return 0.5f * x * (1.0f + erff(x * 0.70710678118654752f));
}

// ---------------------------------------------------------------------------
// Embedding: h[b,t,:] = inp_emb[x[b,t],:] + pos_emb[t,:]
// ---------------------------------------------------------------------------
__global__ __launch_bounds__(256) void embed_kernel(
    const int* __restrict__ x, const float* __restrict__ inp_emb,
    const float* __restrict__ pos_emb, float* __restrict__ h)
{
    const int idx = blockIdx.x * 256 + threadIdx.x;      // over B*T*D
    const int bt  = idx >> 10;          // /D
    const int d   = idx & 1023;         // %D
    const int t   = bt & (SEQ_T - 1);
    const int tok = x[bt];
    h[idx] = inp_emb[(size_t)tok * D_MODEL + d] + pos_emb[(size_t)t * D_MODEL + d];
}

// ---------------------------------------------------------------------------
// LayerNorm over last dim (D=1024). One block (256 thr) per row.
// ---------------------------------------------------------------------------
__global__ __launch_bounds__(256) void layernorm_kernel(
    const float* __restrict__ x, const float* __restrict__ sc,
    const float* __restrict__ bi, float* __restrict__ o)
{
    const int row = blockIdx.x;
    const int tid = threadIdx.x;
    const int c   = tid * 4;
    const float4 v = *(const float4*)(x + (size_t)row * D_MODEL + c);
    float sum = v.x + v.y + v.z + v.w;
    float sq  = v.x * v.x + v.y * v.y + v.z * v.z + v.w * v.w;
    #pragma unroll
    for (int off = 32; off > 0; off >>= 1) {
        sum += __shfl_xor(sum, off);
        sq  += __shfl_xor(sq, off);
    }
    __shared__ float ssum[4], ssq[4];
    const int wave = tid >> 6, lane = tid & 63;
    if (lane == 0) { ssum[wave] = sum; ssq[wave] = sq; }
    __syncthreads();
    sum = ssum[0] + ssum[1] + ssum[2] + ssum[3];
    sq  = ssq[0]  + ssq[1]  + ssq[2]  + ssq[3];
    const float mu  = sum * (1.0f / D_MODEL);
    const float var = sq * (1.0f / D_MODEL) - mu * mu;
    const float rs  = rsqrtf(var + 1e-5f);
    const float4 s4 = *(const float4*)(sc + c);
    const float4 b4 = *(const float4*)(bi + c);
    float4 ov;
    ov.x = (v.x - mu) * rs * s4.x + b4.x;
    ov.y = (v.y - mu) * rs * s4.y + b4.y;
    ov.z = (v.z - mu) * rs * s4.z + b4.z;
    ov.w = (v.w - mu) * rs * s4.w + b4.w;
    *(float4*)(o + (size_t)row * D_MODEL + c) = ov;
}

// ---------------------------------------------------------------------------
// GEMM: C[M,N] = epilogue(A[M,K] @ W[K,N] + bias).  f32 in, bf16 MFMA, f32 out.
// EPI: 0 = bias only; 1 = bias + residual add; 2 = bias + exact GELU.
// ---------------------------------------------------------------------------
template <int EPI>
__global__ __launch_bounds__(256) void gemm_kernel(
    const float* __restrict__ A, const float* __restrict__ W,
    const float* __restrict__ bias, const float* __restrict__ res,
    float* __restrict__ C, int M, int N, int K)
{
    __shared__ __bf16 As[64][40];   // [row][k], +8 pad
    __shared__ __bf16 Bs[64][40];   // [col][k], +8 pad (transposed at stage)
    const int tid  = threadIdx.x;
    const int wave = tid >> 6;
    const int lane = tid & 63;
    const int bm   = blockIdx.y * 64;
    const int bn   = blockIdx.x * 64;

    f32x4 acc[4] = {};

    const int arow = tid >> 2;          // 0..63
    const int acol = (tid & 3) * 8;     // 0,8,16,24
    const int brow = tid >> 3;          // k 0..31
    const int bcol = (tid & 7) * 8;     // col 0..56

    const int r  = lane & 15;
    const int kb = lane >> 4;

    for (int k0 = 0; k0 < K; k0 += 32) {
        const float* ap = A + (size_t)(bm + arow) * K + k0 + acol;
        const float4 a0 = *(const float4*)ap;
        const float4 a1 = *(const float4*)(ap + 4);
        const float* wp = W + (size_t)(k0 + brow) * N + bn + bcol;
        const float4 w0 = *(const float4*)wp;
        const float4 w1 = *(const float4*)(wp + 4);
        As[arow][acol + 0] = (__bf16)a0.x;
        As[arow][acol + 1] = (__bf16)a0.y;
        As[arow][acol + 2] = (__bf16)a0.z;
        As[arow][acol + 3] = (__bf16)a0.w;
        As[arow][acol + 4] = (__bf16)a1.x;
        As[arow][acol + 5] = (__bf16)a1.y;
        As[arow][acol + 6] = (__bf16)a1.z;
        As[arow][acol + 7] = (__bf16)a1.w;
        Bs[bcol + 0][brow] = (__bf16)w0.x;
        Bs[bcol + 1][brow] = (__bf16)w0.y;
        Bs[bcol + 2][brow] = (__bf16)w0.z;
        Bs[bcol + 3][brow] = (__bf16)w0.w;
        Bs[bcol + 4][brow] = (__bf16)w1.x;
        Bs[bcol + 5][brow] = (__bf16)w1.y;
        Bs[bcol + 6][brow] = (__bf16)w1.z;
        Bs[bcol + 7][brow] = (__bf16)w1.w;
        __syncthreads();

        bf16x8 af;
        #pragma unroll
        for (int j = 0; j < 8; ++j) af[j] = As[wave * 16 + r][kb * 8 + j];
        #pragma unroll
        for (int n = 0; n < 4; ++n) {
            bf16x8 bfr;
            #pragma unroll
            for (int j = 0; j < 8; ++j) bfr[j] = Bs[n * 16 + r][kb * 8 + j];
            acc[n] = __builtin_amdgcn_mfma_f32_16x16x32_bf16(af, bfr, acc[n], 0, 0, 0);
        }
        __syncthreads();
    }

    #pragma unroll
    for (int n = 0; n < 4; ++n) {
        #pragma unroll
        for (int rg = 0; rg < 4; ++rg) {
            const int row = bm + wave * 16 + kb * 4 + rg;
            const int col = bn + n * 16 + r;
            float vv = acc[n][rg];
            if (bias) vv += bias[col];
            if (EPI == 1) vv += res[(size_t)row * N + col];
            if (EPI == 2) vv = gelu_f(vv);
            C[(size_t)row * N + col] = vv;
        }
    }
}

// ---------------------------------------------------------------------------
// MFMA flash attention (causal). One block = (b, h, 64-query tile); 4 waves,
// each wave owns 16 queries. Key tiles of 32 staged in LDS as bf16.
//   K_lds[key][dim]   (+8 pad): QK^T B-fragments  = ds_read_b128
//   V_lds[dim][key]   (+8 pad): PV   B-fragments  = ds_read_b128
//   P_lds per wave: P transpose for the PV A-fragment (no barrier needed).
// Online softmax per query row via 16-lane-group shfl_xor reduces.
// ---------------------------------------------------------------------------
__global__ __launch_bounds__(256) void attn_mfma_kernel(
    const float* __restrict__ q, const float* __restrict__ k,
    const float* __restrict__ v, float* __restrict__ y)
{
    __shared__ __align__(16) __bf16 K_lds[32][72];
    __shared__ __align__(16) __bf16 V_lds[64][40];   // [dim][key]
    __shared__ __align__(16) __bf16 P_lds[4][16][40];

    const int tid  = threadIdx.x;
    const int wave = tid >> 6;
    const int lane = tid & 63;
    const int r    = lane & 15;
    const int kb   = lane >> 4;

    const int q0 = blockIdx.x * 64;
    const int bh = blockIdx.y;
    const int b  = bh >> 4;
    const int h  = bh & 15;

    const size_t base = (size_t)b * SEQ_T * D_MODEL + (size_t)h * DKH;

    // Q fragments for this wave's 16 queries, pre-scaled by 1/sqrt(64)
    bf16x8 qf[2];
    {
        const int qrow = q0 + wave * 16 + r;
        const float* qp = q + base + (size_t)qrow * D_MODEL;
        #pragma unroll
        for (int kc = 0; kc < 2; ++kc) {
            const float4 a0 = *(const float4*)(qp + kc * 32 + kb * 8);
            const float4 a1 = *(const float4*)(qp + kc * 32 + kb * 8 + 4);
            qf[kc][0] = (__bf16)(a0.x * 0.125f);
            qf[kc][1] = (__bf16)(a0.y * 0.125f);
            qf[kc][2] = (__bf16)(a0.z * 0.125f);
            qf[kc][3] = (__bf16)(a0.w * 0.125f);
            qf[kc][4] = (__bf16)(a1.x * 0.125f);
            qf[kc][5] = (__bf16)(a1.y * 0.125f);
            qf[kc][6] = (__bf16)(a1.z * 0.125f);
            qf[kc][7] = (__bf16)(a1.w * 0.125f);
        }
    }

    float m_run[4] = {-INFINITY, -INFINITY, -INFINITY, -INFINITY};
    float l_run[4] = {0.0f, 0.0f, 0.0f, 0.0f};
    f32x4 yacc[4] = {};

    // staging indices (256 threads cover 32 keys x 64 dims, 8 floats each)
    const int skey = tid >> 3;          // 0..31
    const int sd0  = (tid & 7) * 8;     // 0..56

    const int ntiles = (q0 + 64) / 32;
    for (int kt = 0; kt < ntiles; ++kt) {
        // ---- stage K (row-major) and V (transposed) as bf16 ----
        {
            const size_t goff = base + (size_t)(kt * 32 + skey) * D_MODEL + sd0;
            const float4 k0 = *(const float4*)(k + goff);
            const float4 k1 = *(const float4*)(k + goff + 4);
            bf16x8 kv;
            kv[0] = (__bf16)k0.x; kv[1] = (__bf16)k0.y;
            kv[2] = (__bf16)k0.z; kv[3] = (__bf16)k0.w;
            kv[4] = (__bf16)k1.x; kv[5] = (__bf16)k1.y;
            kv[6] = (__bf16)k1.z; kv[7] = (__bf16)k1.w;
            *(bf16x8*)&K_lds[skey][sd0] = kv;
            const float4 v0 = *(const float4*)(v + goff);
            const float4 v1 = *(const float4*)(v + goff + 4);
            V_lds[sd0 + 0][skey] = (__bf16)v0.x;
            V_lds[sd0 + 1][skey] = (__bf16)v0.y;
            V_lds[sd0 + 2][skey] = (__bf16)v0.z;
            V_lds[sd0 + 3][skey] = (__bf16)v0.w;
            V_lds[sd0 + 4][skey] = (__bf16)v1.x;
            V_lds[sd0 + 5][skey] = (__bf16)v1.y;
            V_lds[sd0 + 6][skey] = (__bf16)v1.z;
            V_lds[sd0 + 7][skey] = (__bf16)v1.w;
        }
        __syncthreads();

        // ---- S = Q K^T for two 16-key groups ----
        f32x4 sacc[2] = {};
        #pragma unroll
        for (int g = 0; g < 2; ++g) {
            #pragma unroll
            for (int kc = 0; kc < 2; ++kc) {
                bf16x8 kf = *(const bf16x8*)&K_lds[g * 16 + r][kc * 32 + kb * 8];
                sacc[g] = __builtin_amdgcn_mfma_f32_16x16x32_bf16(qf[kc], kf, sacc[g], 0, 0, 0);
            }
        }

        // ---- causal mask + online softmax ----
        float s[2][4], p[2][4];
        #pragma unroll
        for (int g = 0; g < 2; ++g) {
            const int key = kt * 32 + g * 16 + r;
            #pragma unroll
            for (int rg = 0; rg < 4; ++rg) {
                const int qq = q0 + wave * 16 + kb * 4 + rg;
                s[g][rg] = (key <= qq) ? sacc[g][rg] : -INFINITY;
            }
        }
        float mt[4], mn[4], corr[4], psum[4];
        #pragma unroll
        for (int rg = 0; rg < 4; ++rg) mt[rg] = fmaxf(s[0][rg], s[1][rg]);
        #pragma unroll
        for (int off = 1; off < 16; off <<= 1) {
            #pragma unroll
            for (int rg = 0; rg < 4; ++rg) mt[rg] = fmaxf(mt[rg], __shfl_xor(mt[rg], off));
        }
        #pragma unroll
        for (int rg = 0; rg < 4; ++rg) {
            mn[rg] = fmaxf(m_run[rg], mt[rg]);
            p[0][rg] = __expf(s[0][rg] - mn[rg]);
            p[1][rg] = __expf(s[1][rg] - mn[rg]);
            psum[rg] = p[0][rg] + p[1][rg];
        }
        #pragma unroll
        for (int off = 1; off < 16; off <<= 1) {
            #pragma unroll
            for (int rg = 0; rg < 4; ++rg) psum[rg] += __shfl_xor(psum[rg], off);
        }
        #pragma unroll
        for (int rg = 0; rg < 4; ++rg) {
            corr[rg] = __expf(m_run[rg] - mn[rg]);
            l_run[rg] = l_run[rg] * corr[rg] + psum[rg];
            m_run[rg] = mn[rg];
        }
        #pragma unroll
        for (int n = 0; n < 4; ++n) {
            #pragma unroll
            for (int rg = 0; rg < 4; ++rg) yacc[n][rg] *= corr[rg];
        }

        // ---- P to LDS (per-wave region), read back as PV A-fragment ----
        #pragma unroll
        for (int g = 0; g < 2; ++g) {
            #pragma unroll
            for (int rg = 0; rg < 4; ++rg) {
                P_lds[wave][kb * 4 + rg][g * 16 + r] = (__bf16)p[g][rg];
            }
        }
        bf16x8 pa = *(const bf16x8*)&P_lds[wave][r][kb * 8];

        // ---- y += P V ----
        #pragma unroll
        for (int n = 0; n < 4; ++n) {
            bf16x8 vf = *(const bf16x8*)&V_lds[n * 16 + r][kb * 8];
            yacc[n] = __builtin_amdgcn_mfma_f32_16x16x32_bf16(pa, vf, yacc[n], 0, 0, 0);
        }
        __syncthreads();
    }

    // ---- epilogue: y / l ----
    float inv[4];
    #pragma unroll
    for (int rg = 0; rg < 4; ++rg) inv[rg] = 1.0f / l_run[rg];
    #pragma unroll
    for (int n = 0; n < 4; ++n) {
        #pragma unroll
        for (int rg = 0; rg < 4; ++rg) {
            const int row = q0 + wave * 16 + kb * 4 + rg;
            y[base + (size_t)row * D_MODEL + n * 16 + r] = yacc[n][rg] * inv[rg];
        }
    }
}

// ---------------------------------------------------------------------------
extern "C" void kernel_launch(void* const* d_in, const int* in_sizes, int n_in,
                              void* d_out, int out_size, void* d_ws, size_t ws_size,
                              hipStream_t stream)
{
    const int*   x       = (const int*)  d_in[0];
    const float* inp_emb = (const float*)d_in[1];
    const float* pos_emb = (const float*)d_in[2];
    const float* wq = (const float*)d_in[3];
    const float* bq = (const float*)d_in[4];
    const float* wk = (const float*)d_in[5];
    const float* bk = (const float*)d_in[6];
    const float* wv = (const float*)d_in[7];
    const float* bv = (const float*)d_in[8];
    const float* wo = (const float*)d_in[9];
    const float* bo = (const float*)d_in[10];
    const float* w1 = (const float*)d_in[11];
    const float* b1 = (const float*)d_in[12];
    const float* w2 = (const float*)d_in[13];
    const float* b2 = (const float*)d_in[14];
    const float* ln1_s = (const float*)d_in[15];
    const float* ln1_b = (const float*)d_in[16];
    const float* ln2_s = (const float*)d_in[17];
    const float* ln2_b = (const float*)d_in[18];
    const float* lno_s = (const float*)d_in[19];
    const float* lno_b = (const float*)d_in[20];
    const float* w_out = (const float*)d_in[21];

    const size_t NTOK = (size_t)BATCH * SEQ_T;   // 2048
    float* ws  = (float*)d_ws;
    float* h   = ws;
    float* xn  = h   + NTOK * D_MODEL;
    float* qb  = xn  + NTOK * D_MODEL;
    float* kb  = qb  + NTOK * D_MODEL;
    float* vb  = kb  + NTOK * D_MODEL;
    float* yb  = vb  + NTOK * D_MODEL;
    float* mid = yb  + NTOK * D_MODEL;           // NTOK * DFF_

    const int M = (int)NTOK;                     // 2048

    // h = embed
    embed_kernel<<<dim3((M * D_MODEL) / 256), 256, 0, stream>>>(x, inp_emb, pos_emb, h);

    for (int i = 0; i < NLAYERS; ++i) {
        const size_t wOff  = (size_t)i * D_MODEL * D_MODEL;
        const size_t w1Off = (size_t)i * D_MODEL * DFF_;
        const size_t w2Off = (size_t)i * DFF_ * D_MODEL;

        // xn = LN1(h)
        layernorm_kernel<<<dim3(M), 256, 0, stream>>>(h, ln1_s + i * D_MODEL, ln1_b + i * D_MODEL, xn);
        // q,k,v
        gemm_kernel<0><<<dim3(D_MODEL / 64, M / 64), 256, 0, stream>>>(
            xn, wq + wOff, bq + i * D_MODEL, nullptr, qb, M, D_MODEL, D_MODEL);
        gemm_kernel<0><<<dim3(D_MODEL / 64, M / 64), 256, 0, stream>>>(
            xn, wk + wOff, bk + i * D_MODEL, nullptr, kb, M, D_MODEL, D_MODEL);
        gemm_kernel<0><<<dim3(D_MODEL / 64, M / 64), 256, 0, stream>>>(
            xn, wv + wOff, bv + i * D_MODEL, nullptr, vb, M, D_MODEL, D_MODEL);
        // y = attention(q,k,v)
        attn_mfma_kernel<<<dim3(SEQ_T / 64, BATCH * N_HEADS), 256, 0, stream>>>(qb, kb, vb, yb);
        // h = h + y @ wo + bo
        gemm_kernel<1><<<dim3(D_MODEL / 64, M / 64), 256, 0, stream>>>(
            yb, wo + wOff, bo + i * D_MODEL, h, h, M, D_MODEL, D_MODEL);
        // xn = LN2(h)
        layernorm_kernel<<<dim3(M), 256, 0, stream>>>(h, ln2_s + i * D_MODEL, ln2_b + i * D_MODEL, xn);
        // mid = gelu(xn @ w1 + b1)
        gemm_kernel<2><<<dim3(DFF_ / 64, M / 64), 256, 0, stream>>>(
            xn, w1 + w1Off, b1 + i * DFF_, nullptr, mid, M, DFF_, D_MODEL);
        // h = h + mid @ w2 + b2
        gemm_kernel<1><<<dim3(D_MODEL / 64, M / 64), 256, 0, stream>>>(
            mid, w2 + w2Off, b2 + i * D_MODEL, h, h, M, D_MODEL, DFF_);
    }

    // xn = LN_out(h); logits = xn @ w_out
    layernorm_kernel<<<dim3(M), 256, 0, stream>>>(h, lno_s, lno_b, xn);
    gemm_kernel<0><<<dim3(VOCAB / 64, M / 64), 256, 0, stream>>>(
        xn, w_out, nullptr, nullptr, (float*)d_out, M, VOCAB, D_MODEL);
}

// Round 3
// 2235.023 us; speedup vs baseline: 6.4173x; 1.9778x over previous
//
#include <hip/hip_runtime.h>
#include <cmath>

#define D_MODEL 1024
#define N_HEADS 16
#define DKH     64
#define SEQ_T   1024
#define BATCH   2
#define VOCAB   32000
#define DFF_    4096
#define NLAYERS 8

typedef __bf16 bf16x8 __attribute__((ext_vector_type(8)));
typedef __bf16 bf16x4v __attribute__((ext_vector_type(4)));
typedef float  f32x4  __attribute__((ext_vector_type(4)));

__device__ __forceinline__ float gelu_f(float x) {
    return 0.5f * x * (1.0f + erff(x * 0.70710678118654752f));
}

__device__ __forceinline__ void gload_lds16(const void* g, void* l) {
    __builtin_amdgcn_global_load_lds(
        (const __attribute__((address_space(1))) void*)g,
        (__attribute__((address_space(3))) void*)l, 16, 0, 0);
}

// ---------------------------------------------------------------------------
// Embedding: h[b,t,:] = inp_emb[x[b,t],:] + pos_emb[t,:]   (f32 out)
// ---------------------------------------------------------------------------
__global__ __launch_bounds__(256) void embed_kernel(
    const int* __restrict__ x, const float* __restrict__ inp_emb,
    const float* __restrict__ pos_emb, float* __restrict__ h)
{
    const int idx = blockIdx.x * 256 + threadIdx.x;      // over B*T*D
    const int bt  = idx >> 10;
    const int d   = idx & 1023;
    const int t   = bt & (SEQ_T - 1);
    const int tok = x[bt];
    h[idx] = inp_emb[(size_t)tok * D_MODEL + d] + pos_emb[(size_t)t * D_MODEL + d];
}

// ---------------------------------------------------------------------------
// LayerNorm over last dim (D=1024). One block (256 thr) per row. bf16 out.
// ---------------------------------------------------------------------------
__global__ __launch_bounds__(256) void layernorm_kernel(
    const float* __restrict__ x, const float* __restrict__ sc,
    const float* __restrict__ bi, __bf16* __restrict__ o)
{
    const int row = blockIdx.x;
    const int tid = threadIdx.x;
    const int c   = tid * 4;
    const float4 v = *(const float4*)(x + (size_t)row * D_MODEL + c);
    float sum = v.x + v.y + v.z + v.w;
    float sq  = v.x * v.x + v.y * v.y + v.z * v.z + v.w * v.w;
    #pragma unroll
    for (int off = 32; off > 0; off >>= 1) {
        sum += __shfl_xor(sum, off);
        sq  += __shfl_xor(sq, off);
    }
    __shared__ float ssum[4], ssq[4];
    const int wave = tid >> 6, lane = tid & 63;
    if (lane == 0) { ssum[wave] = sum; ssq[wave] = sq; }
    __syncthreads();
    sum = ssum[0] + ssum[1] + ssum[2] + ssum[3];
    sq  = ssq[0]  + ssq[1]  + ssq[2]  + ssq[3];
    const float mu  = sum * (1.0f / D_MODEL);
    const float var = sq * (1.0f / D_MODEL) - mu * mu;
    const float rs  = rsqrtf(var + 1e-5f);
    const float4 s4 = *(const float4*)(sc + c);
    const float4 b4 = *(const float4*)(bi + c);
    bf16x4v ov;
    ov[0] = (__bf16)((v.x - mu) * rs * s4.x + b4.x);
    ov[1] = (__bf16)((v.y - mu) * rs * s4.y + b4.y);
    ov[2] = (__bf16)((v.z - mu) * rs * s4.z + b4.z);
    ov[3] = (__bf16)((v.w - mu) * rs * s4.w + b4.w);
    *(bf16x4v*)(o + (size_t)row * D_MODEL + c) = ov;
}

// ---------------------------------------------------------------------------
// Transpose + convert: in f32 [K][N] -> out bf16 [N][K]. 32x32 tiles, 256 thr.
// ---------------------------------------------------------------------------
__global__ __launch_bounds__(256) void transpose_cvt_kernel(
    const float* __restrict__ in, __bf16* __restrict__ out, int K, int N)
{
    __shared__ __bf16 tile[32][36];
    const int tid = threadIdx.x;
    const int nb0 = blockIdx.x * 32;   // N tile origin
    const int kb0 = blockIdx.y * 32;   // K tile origin
    {
        const int rr = tid >> 3, c4 = (tid & 7) * 4;
        const float4 v = *(const float4*)(in + (size_t)(kb0 + rr) * N + nb0 + c4);
        tile[rr][c4 + 0] = (__bf16)v.x;
        tile[rr][c4 + 1] = (__bf16)v.y;
        tile[rr][c4 + 2] = (__bf16)v.z;
        tile[rr][c4 + 3] = (__bf16)v.w;
    }
    __syncthreads();
    {
        const int cc = tid >> 3, r4 = (tid & 7) * 4;
        bf16x4v ov;
        ov[0] = tile[r4 + 0][cc];
        ov[1] = tile[r4 + 1][cc];
        ov[2] = tile[r4 + 2][cc];
        ov[3] = tile[r4 + 3][cc];
        *(bf16x4v*)(out + (size_t)(nb0 + cc) * K + kb0 + r4) = ov;
    }
}

// ---------------------------------------------------------------------------
// Concat 3x[1024] f32 biases into [3072]
// ---------------------------------------------------------------------------
__global__ __launch_bounds__(256) void concat3_kernel(
    const float* __restrict__ a, const float* __restrict__ b,
    const float* __restrict__ c, float* __restrict__ o)
{
    const int j = blockIdx.x * 256 + threadIdx.x;
    o[j] = (j < 1024) ? a[j] : (j < 2048 ? b[j - 1024] : c[j - 2048]);
}

// ---------------------------------------------------------------------------
// GEMM: C[M,N] = epi(A[M,K] @ Bt[N,K]^T + bias). bf16 in, f32 acc.
// m97 structure: 128 x BN_T tile, BK=32, global_load_lds staging (linear LDS,
// XOR-granule swizzle applied on source and fragment read), 4 waves 2x2,
// 4 x NF fragments/wave. EPI: 0 bias; 1 bias+residual(f32); 2 bias+GELU.
// ---------------------------------------------------------------------------
template <int BN_T, int EPI, typename OutT>
__global__ __launch_bounds__(256) void gemm_bt(
    const __bf16* __restrict__ A, const __bf16* __restrict__ Bt,
    const float* __restrict__ bias, const float* __restrict__ res,
    OutT* __restrict__ C, int M, int N, int K)
{
    constexpr int NF   = BN_T / 32;     // N fragments per wave (4 or 2)
    constexpr int NITB = BN_T / 64;     // B staging iterations (2 or 1)
    __shared__ __bf16 As[128 * 32];
    __shared__ __bf16 Bs[BN_T * 32];

    const int tid  = threadIdx.x;
    const int wave = tid >> 6;
    const int lane = tid & 63;
    const int r    = lane & 15;
    const int kb   = lane >> 4;
    const int wm   = wave >> 1;
    const int wn   = wave & 1;
    const int bm   = blockIdx.y * 128;
    const int bn   = blockIdx.x * BN_T;

    // staging: lane covers LDS row = chunk*16 + lane/4, granule lane&3.
    // source granule swizzled so LDS[row][g] = G[row][g ^ ((row>>1)&3)].
    const int srow = lane >> 2;
    const int scol = ((lane & 3) ^ ((srow >> 1) & 3)) * 8;

    // fragment read offsets (elements), loop-invariant; same swizzle.
    const int fg = (kb ^ ((r >> 1) & 3)) * 8;
    int aoff[4], boff[NF];
    #pragma unroll
    for (int m = 0; m < 4; ++m) aoff[m] = (wm * 64 + m * 16 + r) * 32 + fg;
    #pragma unroll
    for (int n = 0; n < NF; ++n) boff[n] = (wn * (NF * 16) + n * 16 + r) * 32 + fg;

    f32x4 acc[4][NF] = {};

    for (int k0 = 0; k0 < K; k0 += 32) {
        #pragma unroll
        for (int i = 0; i < 2; ++i) {                 // A: 8 chunks of 1KB
            const int c = i * 4 + wave;
            const int row = c * 16 + srow;
            gload_lds16(A + (size_t)(bm + row) * K + k0 + scol, &As[c * 512]);
        }
        #pragma unroll
        for (int i = 0; i < NITB; ++i) {              // B: BN_T/16 chunks
            const int c = i * 4 + wave;
            const int row = c * 16 + srow;
            gload_lds16(Bt + (size_t)(bn + row) * K + k0 + scol, &Bs[c * 512]);
        }
        __syncthreads();

        bf16x8 af[4];
        #pragma unroll
        for (int m = 0; m < 4; ++m) af[m] = *(const bf16x8*)&As[aoff[m]];
        #pragma unroll
        for (int n = 0; n < NF; ++n) {
            const bf16x8 bfr = *(const bf16x8*)&Bs[boff[n]];
            #pragma unroll
            for (int m = 0; m < 4; ++m)
                acc[m][n] = __builtin_amdgcn_mfma_f32_16x16x32_bf16(af[m], bfr, acc[m][n], 0, 0, 0);
        }
        __syncthreads();
    }

    #pragma unroll
    for (int m = 0; m < 4; ++m) {
        const int row = bm + wm * 64 + m * 16 + kb * 4;
        #pragma unroll
        for (int n = 0; n < NF; ++n) {
            const int col = bn + wn * (NF * 16) + n * 16 + r;
            const float bv = bias ? bias[col] : 0.0f;
            #pragma unroll
            for (int rg = 0; rg < 4; ++rg) {
                float v = acc[m][n][rg] + bv;
                if constexpr (EPI == 1) v += res[(size_t)(row + rg) * N + col];
                if constexpr (EPI == 2) v = gelu_f(v);
                C[(size_t)(row + rg) * N + col] = (OutT)v;
            }
        }
    }
}

// ---------------------------------------------------------------------------
// MFMA flash attention (causal), bf16 in (packed qkv, row stride 3072),
// bf16 out (stride 1024). One block = (b,h,64-query tile); 4 waves x 16 q.
// ---------------------------------------------------------------------------
__global__ __launch_bounds__(256) void attn_mfma_kernel(
    const __bf16* __restrict__ qkv, __bf16* __restrict__ y)
{
    constexpr int QS = 3 * D_MODEL;   // 3072
    __shared__ __align__(16) __bf16 K_lds[32][72];
    __shared__ __align__(16) __bf16 V_lds[64][40];   // [dim][key]
    __shared__ __align__(16) __bf16 P_lds[4][16][40];

    const int tid  = threadIdx.x;
    const int wave = tid >> 6;
    const int lane = tid & 63;
    const int r    = lane & 15;
    const int kb   = lane >> 4;

    const int q0 = blockIdx.x * 64;
    const int bh = blockIdx.y;
    const int b  = bh >> 4;
    const int h  = bh & 15;

    const __bf16* qp = qkv + (size_t)b * SEQ_T * QS + h * DKH;
    const __bf16* kp = qp + D_MODEL;
    const __bf16* vp = qp + 2 * D_MODEL;
    __bf16* yp = y + (size_t)b * SEQ_T * D_MODEL + h * DKH;

    // Q fragments (unscaled; 1/sqrt(dk) applied to scores post-MFMA)
    bf16x8 qf[2];
    {
        const int qrow = q0 + wave * 16 + r;
        #pragma unroll
        for (int kc = 0; kc < 2; ++kc)
            qf[kc] = *(const bf16x8*)(qp + (size_t)qrow * QS + kc * 32 + kb * 8);
    }

    float m_run[4] = {-INFINITY, -INFINITY, -INFINITY, -INFINITY};
    float l_run[4] = {0.0f, 0.0f, 0.0f, 0.0f};
    f32x4 yacc[4] = {};

    const int skey = tid >> 3;          // 0..31
    const int sd0  = (tid & 7) * 8;     // 0..56

    const int ntiles = (q0 + 64) / 32;
    for (int kt = 0; kt < ntiles; ++kt) {
        {
            const size_t goff = (size_t)(kt * 32 + skey) * QS + sd0;
            *(bf16x8*)&K_lds[skey][sd0] = *(const bf16x8*)(kp + goff);
            const bf16x8 vv = *(const bf16x8*)(vp + goff);
            #pragma unroll
            for (int j = 0; j < 8; ++j) V_lds[sd0 + j][skey] = vv[j];
        }
        __syncthreads();

        f32x4 sacc[2] = {};
        #pragma unroll
        for (int g = 0; g < 2; ++g) {
            #pragma unroll
            for (int kc = 0; kc < 2; ++kc) {
                bf16x8 kf = *(const bf16x8*)&K_lds[g * 16 + r][kc * 32 + kb * 8];
                sacc[g] = __builtin_amdgcn_mfma_f32_16x16x32_bf16(qf[kc], kf, sacc[g], 0, 0, 0);
            }
        }

        float s[2][4], p[2][4];
        #pragma unroll
        for (int g = 0; g < 2; ++g) {
            const int key = kt * 32 + g * 16 + r;
            #pragma unroll
            for (int rg = 0; rg < 4; ++rg) {
                const int qq = q0 + wave * 16 + kb * 4 + rg;
                s[g][rg] = (key <= qq) ? sacc[g][rg] * 0.125f : -INFINITY;
            }
        }
        float mt[4], mn[4], corr[4], psum[4];
        #pragma unroll
        for (int rg = 0; rg < 4; ++rg) mt[rg] = fmaxf(s[0][rg], s[1][rg]);
        #pragma unroll
        for (int off = 1; off < 16; off <<= 1) {
            #pragma unroll
            for (int rg = 0; rg < 4; ++rg) mt[rg] = fmaxf(mt[rg], __shfl_xor(mt[rg], off));
        }
        #pragma unroll
        for (int rg = 0; rg < 4; ++rg) {
            mn[rg] = fmaxf(m_run[rg], mt[rg]);
            p[0][rg] = __expf(s[0][rg] - mn[rg]);
            p[1][rg] = __expf(s[1][rg] - mn[rg]);
            psum[rg] = p[0][rg] + p[1][rg];
        }
        #pragma unroll
        for (int off = 1; off < 16; off <<= 1) {
            #pragma unroll
            for (int rg = 0; rg < 4; ++rg) psum[rg] += __shfl_xor(psum[rg], off);
        }
        #pragma unroll
        for (int rg = 0; rg < 4; ++rg) {
            corr[rg] = __expf(m_run[rg] - mn[rg]);
            l_run[rg] = l_run[rg] * corr[rg] + psum[rg];
            m_run[rg] = mn[rg];
        }
        #pragma unroll
        for (int n = 0; n < 4; ++n) {
            #pragma unroll
            for (int rg = 0; rg < 4; ++rg) yacc[n][rg] *= corr[rg];
        }

        #pragma unroll
        for (int g = 0; g < 2; ++g) {
            #pragma unroll
            for (int rg = 0; rg < 4; ++rg)
                P_lds[wave][kb * 4 + rg][g * 16 + r] = (__bf16)p[g][rg];
        }
        bf16x8 pa = *(const bf16x8*)&P_lds[wave][r][kb * 8];

        #pragma unroll
        for (int n = 0; n < 4; ++n) {
            bf16x8 vf = *(const bf16x8*)&V_lds[n * 16 + r][kb * 8];
            yacc[n] = __builtin_amdgcn_mfma_f32_16x16x32_bf16(pa, vf, yacc[n], 0, 0, 0);
        }
        __syncthreads();
    }

    float inv[4];
    #pragma unroll
    for (int rg = 0; rg < 4; ++rg) inv[rg] = 1.0f / l_run[rg];
    #pragma unroll
    for (int n = 0; n < 4; ++n) {
        #pragma unroll
        for (int rg = 0; rg < 4; ++rg) {
            const int row = q0 + wave * 16 + kb * 4 + rg;
            yp[(size_t)row * D_MODEL + n * 16 + r] = (__bf16)(yacc[n][rg] * inv[rg]);
        }
    }
}

// ---------------------------------------------------------------------------
extern "C" void kernel_launch(void* const* d_in, const int* in_sizes, int n_in,
                              void* d_out, int out_size, void* d_ws, size_t ws_size,
                              hipStream_t stream)
{
    const int*   x       = (const int*)  d_in[0];
    const float* inp_emb = (const float*)d_in[1];
    const float* pos_emb = (const float*)d_in[2];
    const float* wq = (const float*)d_in[3];
    const float* bq = (const float*)d_in[4];
    const float* wk = (const float*)d_in[5];
    const float* bk = (const float*)d_in[6];
    const float* wv = (const float*)d_in[7];
    const float* bv = (const float*)d_in[8];
    const float* wo = (const float*)d_in[9];
    const float* bo = (const float*)d_in[10];
    const float* w1 = (const float*)d_in[11];
    const float* b1 = (const float*)d_in[12];
    const float* w2 = (const float*)d_in[13];
    const float* b2 = (const float*)d_in[14];
    const float* ln1_s = (const float*)d_in[15];
    const float* ln1_b = (const float*)d_in[16];
    const float* ln2_s = (const float*)d_in[17];
    const float* ln2_b = (const float*)d_in[18];
    const float* lno_s = (const float*)d_in[19];
    const float* lno_b = (const float*)d_in[20];
    const float* w_out = (const float*)d_in[21];

    const int M = BATCH * SEQ_T;                 // 2048
    const size_t MB = 1u << 20;

    char* w = (char*)d_ws;
    float*  h     = (float*) (w + 0);            // [2048][1024] f32   8MB
    __bf16* xn    = (__bf16*)(w + 8  * MB);      // [2048][1024] bf16  4MB
    __bf16* yb    = (__bf16*)(w + 12 * MB);      // [2048][1024] bf16  4MB
    __bf16* sh    = (__bf16*)(w + 16 * MB);      // qkv [2048][3072] | mid [2048][4096]  16MB
    __bf16* wqkvT = (__bf16*)(w + 32 * MB);      // [3072][1024]       6MB
    __bf16* woT   = (__bf16*)(w + 38 * MB);      // [1024][1024]       2MB
    __bf16* w1T   = (__bf16*)(w + 40 * MB);      // [4096][1024]       8MB
    __bf16* w2T   = (__bf16*)(w + 48 * MB);      // [1024][4096]       8MB
    float*  bqkv  = (float*) (w + 56 * MB);      // [3072]
    __bf16* woutT = (__bf16*)(w + 57 * MB);      // [32000][1024]      62.5MB

    embed_kernel<<<dim3(M * D_MODEL / 256), 256, 0, stream>>>(x, inp_emb, pos_emb, h);

    for (int i = 0; i < NLAYERS; ++i) {
        const size_t wOff  = (size_t)i * D_MODEL * D_MODEL;
        const size_t w1Off = (size_t)i * D_MODEL * DFF_;

        // weight conversions for this layer (bf16, transposed to [N][K])
        transpose_cvt_kernel<<<dim3(32, 32),  256, 0, stream>>>(wq + wOff, wqkvT,                  D_MODEL, D_MODEL);
        transpose_cvt_kernel<<<dim3(32, 32),  256, 0, stream>>>(wk + wOff, wqkvT + 1024 * 1024,    D_MODEL, D_MODEL);
        transpose_cvt_kernel<<<dim3(32, 32),  256, 0, stream>>>(wv + wOff, wqkvT + 2048 * 1024,    D_MODEL, D_MODEL);
        transpose_cvt_kernel<<<dim3(32, 32),  256, 0, stream>>>(wo + wOff, woT,                    D_MODEL, D_MODEL);
        transpose_cvt_kernel<<<dim3(128, 32), 256, 0, stream>>>(w1 + w1Off, w1T,                   D_MODEL, DFF_);
        transpose_cvt_kernel<<<dim3(32, 128), 256, 0, stream>>>(w2 + w1Off, w2T,                   DFF_, D_MODEL);
        concat3_kernel<<<dim3(12), 256, 0, stream>>>(bq + i * D_MODEL, bk + i * D_MODEL, bv + i * D_MODEL, bqkv);

        // xn = LN1(h)
        layernorm_kernel<<<dim3(M), 256, 0, stream>>>(h, ln1_s + i * D_MODEL, ln1_b + i * D_MODEL, xn);
        // qkv = xn @ [wq|wk|wv] + [bq|bk|bv]
        gemm_bt<128, 0, __bf16><<<dim3(3 * D_MODEL / 128, M / 128), 256, 0, stream>>>(
            xn, wqkvT, bqkv, nullptr, sh, M, 3 * D_MODEL, D_MODEL);
        // y = attention(qkv)
        attn_mfma_kernel<<<dim3(SEQ_T / 64, BATCH * N_HEADS), 256, 0, stream>>>(sh, yb);
        // h = h + y @ wo + bo
        gemm_bt<64, 1, float><<<dim3(D_MODEL / 64, M / 128), 256, 0, stream>>>(
            yb, woT, bo + i * D_MODEL, h, h, M, D_MODEL, D_MODEL);
        // xn = LN2(h)
        layernorm_kernel<<<dim3(M), 256, 0, stream>>>(h, ln2_s + i * D_MODEL, ln2_b + i * D_MODEL, xn);
        // mid = gelu(xn @ w1 + b1)
        gemm_bt<128, 2, __bf16><<<dim3(DFF_ / 128, M / 128), 256, 0, stream>>>(
            xn, w1T, b1 + i * DFF_, nullptr, sh, M, DFF_, D_MODEL);
        // h = h + mid @ w2 + b2
        gemm_bt<64, 1, float><<<dim3(D_MODEL / 64, M / 128), 256, 0, stream>>>(
            sh, w2T, b2 + i * D_MODEL, h, h, M, D_MODEL, DFF_);
    }

    // final: transpose w_out, LN, logits
    transpose_cvt_kernel<<<dim3(VOCAB / 32, 32), 256, 0, stream>>>(w_out, woutT, D_MODEL, VOCAB);
    layernorm_kernel<<<dim3(M), 256, 0, stream>>>(h, lno_s, lno_b, xn);
    gemm_bt<128, 0, float><<<dim3(VOCAB / 128, M / 128), 256, 0, stream>>>(
        xn, woutT, nullptr, nullptr, (float*)d_out, M, VOCAB, D_MODEL);
}

// Round 4
// 1946.160 us; speedup vs baseline: 7.3698x; 1.1484x over previous
//
#include <hip/hip_runtime.h>
#include <cmath>

#define D_MODEL 1024
#define N_HEADS 16
#define DKH     64
#define SEQ_T   1024
#define BATCH   2
#define VOCAB   32000
#define DFF_    4096
#define NLAYERS 8

typedef __bf16 bf16x8 __attribute__((ext_vector_type(8)));
typedef __bf16 bf16x4v __attribute__((ext_vector_type(4)));
typedef float  f32x4  __attribute__((ext_vector_type(4)));

__device__ __forceinline__ float gelu_f(float x) {
    return 0.5f * x * (1.0f + erff(x * 0.70710678118654752f));
}

__device__ __forceinline__ void gload_lds16(const void* g, void* l) {
    __builtin_amdgcn_global_load_lds(
        (const __attribute__((address_space(1))) void*)g,
        (__attribute__((address_space(3))) void*)l, 16, 0, 0);
}

// ---------------------------------------------------------------------------
// Embedding
// ---------------------------------------------------------------------------
__global__ __launch_bounds__(256) void embed_kernel(
    const int* __restrict__ x, const float* __restrict__ inp_emb,
    const float* __restrict__ pos_emb, float* __restrict__ h)
{
    const int idx = blockIdx.x * 256 + threadIdx.x;
    const int bt  = idx >> 10;
    const int d   = idx & 1023;
    const int t   = bt & (SEQ_T - 1);
    const int tok = x[bt];
    h[idx] = inp_emb[(size_t)tok * D_MODEL + d] + pos_emb[(size_t)t * D_MODEL + d];
}

// ---------------------------------------------------------------------------
// LayerNorm (D=1024), one 256-thr block per row, bf16 out.
// ---------------------------------------------------------------------------
__global__ __launch_bounds__(256) void layernorm_kernel(
    const float* __restrict__ x, const float* __restrict__ sc,
    const float* __restrict__ bi, __bf16* __restrict__ o)
{
    const int row = blockIdx.x;
    const int tid = threadIdx.x;
    const int c   = tid * 4;
    const float4 v = *(const float4*)(x + (size_t)row * D_MODEL + c);
    float sum = v.x + v.y + v.z + v.w;
    float sq  = v.x * v.x + v.y * v.y + v.z * v.z + v.w * v.w;
    #pragma unroll
    for (int off = 32; off > 0; off >>= 1) {
        sum += __shfl_xor(sum, off);
        sq  += __shfl_xor(sq, off);
    }
    __shared__ float ssum[4], ssq[4];
    const int wave = tid >> 6, lane = tid & 63;
    if (lane == 0) { ssum[wave] = sum; ssq[wave] = sq; }
    __syncthreads();
    sum = ssum[0] + ssum[1] + ssum[2] + ssum[3];
    sq  = ssq[0]  + ssq[1]  + ssq[2]  + ssq[3];
    const float mu  = sum * (1.0f / D_MODEL);
    const float var = sq * (1.0f / D_MODEL) - mu * mu;
    const float rs  = rsqrtf(var + 1e-5f);
    const float4 s4 = *(const float4*)(sc + c);
    const float4 b4 = *(const float4*)(bi + c);
    bf16x4v ov;
    ov[0] = (__bf16)((v.x - mu) * rs * s4.x + b4.x);
    ov[1] = (__bf16)((v.y - mu) * rs * s4.y + b4.y);
    ov[2] = (__bf16)((v.z - mu) * rs * s4.z + b4.z);
    ov[3] = (__bf16)((v.w - mu) * rs * s4.w + b4.w);
    *(bf16x4v*)(o + (size_t)row * D_MODEL + c) = ov;
}

// ---------------------------------------------------------------------------
// Fused per-layer weight prep: all 6 transposes (f32 [K][N] -> bf16 [N][K])
// + qkv bias concat in ONE dispatch. Block-id range decode, 32x32 tiles.
// ---------------------------------------------------------------------------
__global__ __launch_bounds__(256) void prep_layer_kernel(
    const float* __restrict__ wq, const float* __restrict__ wk,
    const float* __restrict__ wv, const float* __restrict__ wo,
    const float* __restrict__ w1, const float* __restrict__ w2,
    const float* __restrict__ bq, const float* __restrict__ bk,
    const float* __restrict__ bv,
    __bf16* __restrict__ wqkvT, __bf16* __restrict__ woT,
    __bf16* __restrict__ w1T, __bf16* __restrict__ w2T,
    float* __restrict__ bqkv)
{
    __shared__ __bf16 tile[32][36];
    const int b   = blockIdx.x;
    const int tid = threadIdx.x;

    if (b >= 12288) {  // bias concat: 12 blocks x 256
        const int j = (b - 12288) * 256 + tid;
        bqkv[j] = (j < 1024) ? bq[j] : (j < 2048 ? bk[j - 1024] : bv[j - 2048]);
        return;
    }

    const float* in;
    __bf16* out;
    int K, N, kb0, nb0;
    if (b < 4096) {            // wq/wk/wv/wo, 1024 tiles each
        const int w = b >> 10, t = b & 1023;
        K = 1024; N = 1024; kb0 = (t >> 5) * 32; nb0 = (t & 31) * 32;
        in  = (w == 0) ? wq : (w == 1) ? wk : (w == 2) ? wv : wo;
        out = (w == 3) ? woT : wqkvT + (size_t)w * 1024 * 1024;
    } else if (b < 8192) {     // w1: K=1024, N=4096
        const int t = b - 4096;
        K = 1024; N = 4096; kb0 = (t >> 7) * 32; nb0 = (t & 127) * 32;
        in = w1; out = w1T;
    } else {                   // w2: K=4096, N=1024
        const int t = b - 8192;
        K = 4096; N = 1024; kb0 = (t >> 5) * 32; nb0 = (t & 31) * 32;
        in = w2; out = w2T;
    }

    {
        const int rr = tid >> 3, c4 = (tid & 7) * 4;
        const float4 v = *(const float4*)(in + (size_t)(kb0 + rr) * N + nb0 + c4);
        tile[rr][c4 + 0] = (__bf16)v.x;
        tile[rr][c4 + 1] = (__bf16)v.y;
        tile[rr][c4 + 2] = (__bf16)v.z;
        tile[rr][c4 + 3] = (__bf16)v.w;
    }
    __syncthreads();
    {
        const int cc = tid >> 3, r4 = (tid & 7) * 4;
        bf16x4v ov;
        ov[0] = tile[r4 + 0][cc];
        ov[1] = tile[r4 + 1][cc];
        ov[2] = tile[r4 + 2][cc];
        ov[3] = tile[r4 + 3][cc];
        *(bf16x4v*)(out + (size_t)(nb0 + cc) * K + kb0 + r4) = ov;
    }
}

// ---------------------------------------------------------------------------
// GEMM: C[M,N] = epi(A[M,K] @ Bt[N,K]^T + bias). bf16 in, f32 acc.
// 128 x BN_T tile, BK=64, global_load_lds staging (linear LDS dest,
// XOR-granule swizzle g^=(row&7) applied on source AND fragment read),
// M-fast grid order + XCD-chunked swizzle for B-panel L2 reuse.
// EPI: 0 bias; 1 bias+residual(f32); 2 bias+GELU.
// ---------------------------------------------------------------------------
template <int BN_T, int EPI, typename OutT>
__global__ __launch_bounds__(256) void gemm_bt(
    const __bf16* __restrict__ A, const __bf16* __restrict__ Bt,
    const float* __restrict__ bias, const float* __restrict__ res,
    OutT* __restrict__ C, int M, int N, int K)
{
    constexpr int NF  = BN_T / 32;      // N fragments per wave (4 or 2)
    constexpr int NCB = BN_T / 8;       // B 1KB-chunks (16 or 8)
    __shared__ __bf16 As[128 * 64];
    __shared__ __bf16 Bs[BN_T * 64];

    const int tid  = threadIdx.x;
    const int wave = tid >> 6;
    const int lane = tid & 63;
    const int r    = lane & 15;
    const int kb   = lane >> 4;
    const int wm   = wave >> 1;
    const int wn   = wave & 1;

    // M-fast linear id + XCD chunking (bijective when nwg % 8 == 0)
    const int ntm = gridDim.x;                     // M/128 (fast axis)
    const int nwg = ntm * gridDim.y;
    int bid = blockIdx.y * ntm + blockIdx.x;
    if ((nwg & 7) == 0) bid = (bid & 7) * (nwg >> 3) + (bid >> 3);
    const int bm = (bid % ntm) * 128;
    const int bn = (bid / ntm) * BN_T;

    // staging decode: 1KB chunk = 8 rows of 64 bf16; lane -> (row, granule)
    const int srow = lane >> 3;         // 0..7
    const int sg   = lane & 7;          // 0..7

    f32x4 acc[4][NF] = {};

    for (int k0 = 0; k0 < K; k0 += 64) {
        #pragma unroll
        for (int i = 0; i < 4; ++i) {               // A: 16 chunks
            const int c   = i * 4 + wave;
            const int row = c * 8 + srow;
            const int scol = (sg ^ (row & 7)) * 8;
            gload_lds16(A + (size_t)(bm + row) * K + k0 + scol, &As[c * 512]);
        }
        #pragma unroll
        for (int i = 0; i < NCB / 4; ++i) {         // B: NCB chunks
            const int c   = i * 4 + wave;
            const int row = c * 8 + srow;
            const int scol = (sg ^ (row & 7)) * 8;
            gload_lds16(Bt + (size_t)(bn + row) * K + k0 + scol, &Bs[c * 512]);
        }
        __syncthreads();

        #pragma unroll
        for (int s = 0; s < 2; ++s) {
            bf16x8 af[4];
            #pragma unroll
            for (int m = 0; m < 4; ++m) {
                const int row = wm * 64 + m * 16 + r;
                const int g   = (s * 4 + kb) ^ (row & 7);
                af[m] = *(const bf16x8*)&As[row * 64 + g * 8];
            }
            #pragma unroll
            for (int n = 0; n < NF; ++n) {
                const int row = wn * (NF * 16) + n * 16 + r;
                const int g   = (s * 4 + kb) ^ (row & 7);
                const bf16x8 bfr = *(const bf16x8*)&Bs[row * 64 + g * 8];
                #pragma unroll
                for (int m = 0; m < 4; ++m)
                    acc[m][n] = __builtin_amdgcn_mfma_f32_16x16x32_bf16(af[m], bfr, acc[m][n], 0, 0, 0);
            }
        }
        __syncthreads();
    }

    #pragma unroll
    for (int m = 0; m < 4; ++m) {
        const int row = bm + wm * 64 + m * 16 + kb * 4;
        #pragma unroll
        for (int n = 0; n < NF; ++n) {
            const int col = bn + wn * (NF * 16) + n * 16 + r;
            const float bv = bias ? bias[col] : 0.0f;
            #pragma unroll
            for (int rg = 0; rg < 4; ++rg) {
                float v = acc[m][n][rg] + bv;
                if constexpr (EPI == 1) v += res[(size_t)(row + rg) * N + col];
                if constexpr (EPI == 2) v = gelu_f(v);
                C[(size_t)(row + rg) * N + col] = (OutT)v;
            }
        }
    }
}

// ---------------------------------------------------------------------------
// MFMA flash attention (causal), bf16 packed qkv in (row stride 3072),
// bf16 out. One block = (b,h,64-query tile); 4 waves x 16 queries.
// V transpose-stage uses XOR key-swizzle (write was 16-way bank conflict).
// ---------------------------------------------------------------------------
__global__ __launch_bounds__(256) void attn_mfma_kernel(
    const __bf16* __restrict__ qkv, __bf16* __restrict__ y)
{
    constexpr int QS = 3 * D_MODEL;
    __shared__ __align__(16) __bf16 K_lds[32][72];
    __shared__ __align__(16) __bf16 V_lds[64][40];   // [dim][key^c(dim)]
    __shared__ __align__(16) __bf16 P_lds[4][16][40];

    const int tid  = threadIdx.x;
    const int wave = tid >> 6;
    const int lane = tid & 63;
    const int r    = lane & 15;
    const int kb   = lane >> 4;

    const int q0 = blockIdx.x * 64;
    const int bh = blockIdx.y;
    const int b  = bh >> 4;
    const int h  = bh & 15;

    const __bf16* qp = qkv + (size_t)b * SEQ_T * QS + h * DKH;
    const __bf16* kp = qp + D_MODEL;
    const __bf16* vp = qp + 2 * D_MODEL;
    __bf16* yp = y + (size_t)b * SEQ_T * D_MODEL + h * DKH;

    bf16x8 qf[2];
    {
        const int qrow = q0 + wave * 16 + r;
        #pragma unroll
        for (int kc = 0; kc < 2; ++kc)
            qf[kc] = *(const bf16x8*)(qp + (size_t)qrow * QS + kc * 32 + kb * 8);
    }

    float m_run[4] = {-INFINITY, -INFINITY, -INFINITY, -INFINITY};
    float l_run[4] = {0.0f, 0.0f, 0.0f, 0.0f};
    f32x4 yacc[4] = {};

    const int skey = tid >> 3;
    const int sd0  = (tid & 7) * 8;

    const int ntiles = (q0 + 64) / 32;
    for (int kt = 0; kt < ntiles; ++kt) {
        {
            const size_t goff = (size_t)(kt * 32 + skey) * QS + sd0;
            *(bf16x8*)&K_lds[skey][sd0] = *(const bf16x8*)(kp + goff);
            const bf16x8 vv = *(const bf16x8*)(vp + goff);
            #pragma unroll
            for (int j = 0; j < 8; ++j) {
                const int d = sd0 + j;
                V_lds[d][skey ^ (((d >> 3) & 3) << 3)] = vv[j];
            }
        }
        __syncthreads();

        f32x4 sacc[2] = {};
        #pragma unroll
        for (int g = 0; g < 2; ++g) {
            #pragma unroll
            for (int kc = 0; kc < 2; ++kc) {
                bf16x8 kf = *(const bf16x8*)&K_lds[g * 16 + r][kc * 32 + kb * 8];
                sacc[g] = __builtin_amdgcn_mfma_f32_16x16x32_bf16(qf[kc], kf, sacc[g], 0, 0, 0);
            }
        }

        float s[2][4], p[2][4];
        #pragma unroll
        for (int g = 0; g < 2; ++g) {
            const int key = kt * 32 + g * 16 + r;
            #pragma unroll
            for (int rg = 0; rg < 4; ++rg) {
                const int qq = q0 + wave * 16 + kb * 4 + rg;
                s[g][rg] = (key <= qq) ? sacc[g][rg] * 0.125f : -INFINITY;
            }
        }
        float mt[4], mn[4], corr[4], psum[4];
        #pragma unroll
        for (int rg = 0; rg < 4; ++rg) mt[rg] = fmaxf(s[0][rg], s[1][rg]);
        #pragma unroll
        for (int off = 1; off < 16; off <<= 1) {
            #pragma unroll
            for (int rg = 0; rg < 4; ++rg) mt[rg] = fmaxf(mt[rg], __shfl_xor(mt[rg], off));
        }
        #pragma unroll
        for (int rg = 0; rg < 4; ++rg) {
            mn[rg] = fmaxf(m_run[rg], mt[rg]);
            p[0][rg] = __expf(s[0][rg] - mn[rg]);
            p[1][rg] = __expf(s[1][rg] - mn[rg]);
            psum[rg] = p[0][rg] + p[1][rg];
        }
        #pragma unroll
        for (int off = 1; off < 16; off <<= 1) {
            #pragma unroll
            for (int rg = 0; rg < 4; ++rg) psum[rg] += __shfl_xor(psum[rg], off);
        }
        #pragma unroll
        for (int rg = 0; rg < 4; ++rg) {
            corr[rg] = __expf(m_run[rg] - mn[rg]);
            l_run[rg] = l_run[rg] * corr[rg] + psum[rg];
            m_run[rg] = mn[rg];
        }
        #pragma unroll
        for (int n = 0; n < 4; ++n) {
            #pragma unroll
            for (int rg = 0; rg < 4; ++rg) yacc[n][rg] *= corr[rg];
        }

        #pragma unroll
        for (int g = 0; g < 2; ++g) {
            #pragma unroll
            for (int rg = 0; rg < 4; ++rg)
                P_lds[wave][kb * 4 + rg][g * 16 + r] = (__bf16)p[g][rg];
        }
        bf16x8 pa = *(const bf16x8*)&P_lds[wave][r][kb * 8];

        #pragma unroll
        for (int n = 0; n < 4; ++n) {
            const int vrow = n * 16 + r;
            bf16x8 vf = *(const bf16x8*)&V_lds[vrow][(kb * 8) ^ (((vrow >> 3) & 3) << 3)];
            yacc[n] = __builtin_amdgcn_mfma_f32_16x16x32_bf16(pa, vf, yacc[n], 0, 0, 0);
        }
        __syncthreads();
    }

    float inv[4];
    #pragma unroll
    for (int rg = 0; rg < 4; ++rg) inv[rg] = 1.0f / l_run[rg];
    #pragma unroll
    for (int n = 0; n < 4; ++n) {
        #pragma unroll
        for (int rg = 0; rg < 4; ++rg) {
            const int row = q0 + wave * 16 + kb * 4 + rg;
            yp[(size_t)row * D_MODEL + n * 16 + r] = (__bf16)(yacc[n][rg] * inv[rg]);
        }
    }
}

// ---------------------------------------------------------------------------
extern "C" void kernel_launch(void* const* d_in, const int* in_sizes, int n_in,
                              void* d_out, int out_size, void* d_ws, size_t ws_size,
                              hipStream_t stream)
{
    const int*   x       = (const int*)  d_in[0];
    const float* inp_emb = (const float*)d_in[1];
    const float* pos_emb = (const float*)d_in[2];
    const float* wq = (const float*)d_in[3];
    const float* bq = (const float*)d_in[4];
    const float* wk = (const float*)d_in[5];
    const float* bk = (const float*)d_in[6];
    const float* wv = (const float*)d_in[7];
    const float* bv = (const float*)d_in[8];
    const float* wo = (const float*)d_in[9];
    const float* bo = (const float*)d_in[10];
    const float* w1 = (const float*)d_in[11];
    const float* b1 = (const float*)d_in[12];
    const float* w2 = (const float*)d_in[13];
    const float* b2 = (const float*)d_in[14];
    const float* ln1_s = (const float*)d_in[15];
    const float* ln1_b = (const float*)d_in[16];
    const float* ln2_s = (const float*)d_in[17];
    const float* ln2_b = (const float*)d_in[18];
    const float* lno_s = (const float*)d_in[19];
    const float* lno_b = (const float*)d_in[20];
    const float* w_out = (const float*)d_in[21];

    const int M = BATCH * SEQ_T;                 // 2048
    const size_t MB = 1u << 20;

    char* w = (char*)d_ws;
    float*  h     = (float*) (w + 0);            // 8MB
    __bf16* xn    = (__bf16*)(w + 8  * MB);      // 4MB
    __bf16* yb    = (__bf16*)(w + 12 * MB);      // 4MB
    __bf16* sh    = (__bf16*)(w + 16 * MB);      // qkv/mid 16MB
    __bf16* wqkvT = (__bf16*)(w + 32 * MB);      // 6MB
    __bf16* woT   = (__bf16*)(w + 38 * MB);      // 2MB
    __bf16* w1T   = (__bf16*)(w + 40 * MB);      // 8MB
    __bf16* w2T   = (__bf16*)(w + 48 * MB);      // 8MB
    float*  bqkv  = (float*) (w + 56 * MB);      // 12KB
    __bf16* woutT = (__bf16*)(w + 57 * MB);      // 62.5MB

    embed_kernel<<<dim3(M * D_MODEL / 256), 256, 0, stream>>>(x, inp_emb, pos_emb, h);

    for (int i = 0; i < NLAYERS; ++i) {
        const size_t wOff  = (size_t)i * D_MODEL * D_MODEL;
        const size_t w1Off = (size_t)i * D_MODEL * DFF_;

        prep_layer_kernel<<<dim3(12300), 256, 0, stream>>>(
            wq + wOff, wk + wOff, wv + wOff, wo + wOff, w1 + w1Off, w2 + w1Off,
            bq + i * D_MODEL, bk + i * D_MODEL, bv + i * D_MODEL,
            wqkvT, woT, w1T, w2T, bqkv);

        layernorm_kernel<<<dim3(M), 256, 0, stream>>>(h, ln1_s + i * D_MODEL, ln1_b + i * D_MODEL, xn);
        gemm_bt<128, 0, __bf16><<<dim3(M / 128, 3 * D_MODEL / 128), 256, 0, stream>>>(
            xn, wqkvT, bqkv, nullptr, sh, M, 3 * D_MODEL, D_MODEL);
        attn_mfma_kernel<<<dim3(SEQ_T / 64, BATCH * N_HEADS), 256, 0, stream>>>(sh, yb);
        gemm_bt<64, 1, float><<<dim3(M / 128, D_MODEL / 64), 256, 0, stream>>>(
            yb, woT, bo + i * D_MODEL, h, h, M, D_MODEL, D_MODEL);
        layernorm_kernel<<<dim3(M), 256, 0, stream>>>(h, ln2_s + i * D_MODEL, ln2_b + i * D_MODEL, xn);
        gemm_bt<128, 2, __bf16><<<dim3(M / 128, DFF_ / 128), 256, 0, stream>>>(
            xn, w1T, b1 + i * DFF_, nullptr, sh, M, DFF_, D_MODEL);
        gemm_bt<64, 1, float><<<dim3(M / 128, D_MODEL / 64), 256, 0, stream>>>(
            sh, w2T, b2 + i * D_MODEL, h, h, M, D_MODEL, DFF_);
    }

    // final: transpose w_out (reuse generic path via prep? simpler: dedicated loop)
    // w_out: f32 [1024][32000] -> bf16 [32000][1024]
    {
        // use prep-style 32x32 transpose with a small dedicated kernel inline:
        // reuse transpose via prep_layer would need ranges; do a lambda-kernel.
    }
    // dedicated transpose for w_out
    extern __global__ void wout_tr_kernel(const float*, __bf16*);
    wout_tr_kernel<<<dim3((VOCAB / 32) * 32), 256, 0, stream>>>(w_out, woutT);

    layernorm_kernel<<<dim3(M), 256, 0, stream>>>(h, lno_s, lno_b, xn);
    gemm_bt<128, 0, float><<<dim3(M / 128, VOCAB / 128), 256, 0, stream>>>(
        xn, woutT, nullptr, nullptr, (float*)d_out, M, VOCAB, D_MODEL);
}

// ---------------------------------------------------------------------------
// w_out transpose: f32 [1024][32000] -> bf16 [32000][1024]. 32x32 tiles;
// blockIdx.x = nb * 32 + kb  (nb < 1000, kb < 32).
// ---------------------------------------------------------------------------
__global__ __launch_bounds__(256) void wout_tr_kernel(
    const float* __restrict__ in, __bf16* __restrict__ out)
{
    __shared__ __bf16 tile[32][36];
    const int tid = threadIdx.x;
    const int nb0 = (blockIdx.x >> 5) * 32;
    const int kb0 = (blockIdx.x & 31) * 32;
    {
        const int rr = tid >> 3, c4 = (tid & 7) * 4;
        const float4 v = *(const float4*)(in + (size_t)(kb0 + rr) * VOCAB + nb0 + c4);
        tile[rr][c4 + 0] = (__bf16)v.x;
        tile[rr][c4 + 1] = (__bf16)v.y;
        tile[rr][c4 + 2] = (__bf16)v.z;
        tile[rr][c4 + 3] = (__bf16)v.w;
    }
    __syncthreads();
    {
        const int cc = tid >> 3, r4 = (tid & 7) * 4;
        bf16x4v ov;
        ov[0] = tile[r4 + 0][cc];
        ov[1] = tile[r4 + 1][cc];
        ov[2] = tile[r4 + 2][cc];
        ov[3] = tile[r4 + 3][cc];
        *(bf16x4v*)(out + (size_t)(nb0 + cc) * D_MODEL + kb0 + r4) = ov;
    }
}

// Round 5
// 1830.316 us; speedup vs baseline: 7.8362x; 1.0633x over previous
//
#include <hip/hip_runtime.h>
#include <cmath>

#define D_MODEL 1024
#define N_HEADS 16
#define DKH     64
#define SEQ_T   1024
#define BATCH   2
#define VOCAB   32000
#define DFF_    4096
#define NLAYERS 8

typedef __bf16 bf16x8 __attribute__((ext_vector_type(8)));
typedef __bf16 bf16x4v __attribute__((ext_vector_type(4)));
typedef float  f32x4  __attribute__((ext_vector_type(4)));

__device__ __forceinline__ float gelu_f(float x) {
    return 0.5f * x * (1.0f + erff(x * 0.70710678118654752f));
}

__device__ __forceinline__ void gload_lds16(const void* g, void* l) {
    __builtin_amdgcn_global_load_lds(
        (const __attribute__((address_space(1))) void*)g,
        (__attribute__((address_space(3))) void*)l, 16, 0, 0);
}

// ---------------------------------------------------------------------------
// Embedding
// ---------------------------------------------------------------------------
__global__ __launch_bounds__(256) void embed_kernel(
    const int* __restrict__ x, const float* __restrict__ inp_emb,
    const float* __restrict__ pos_emb, float* __restrict__ h)
{
    const int idx = blockIdx.x * 256 + threadIdx.x;
    const int bt  = idx >> 10;
    const int d   = idx & 1023;
    const int t   = bt & (SEQ_T - 1);
    const int tok = x[bt];
    h[idx] = inp_emb[(size_t)tok * D_MODEL + d] + pos_emb[(size_t)t * D_MODEL + d];
}

// ---------------------------------------------------------------------------
// LayerNorm (D=1024), one 256-thr block per row, bf16 out.
// ---------------------------------------------------------------------------
__global__ __launch_bounds__(256) void layernorm_kernel(
    const float* __restrict__ x, const float* __restrict__ sc,
    const float* __restrict__ bi, __bf16* __restrict__ o)
{
    const int row = blockIdx.x;
    const int tid = threadIdx.x;
    const int c   = tid * 4;
    const float4 v = *(const float4*)(x + (size_t)row * D_MODEL + c);
    float sum = v.x + v.y + v.z + v.w;
    float sq  = v.x * v.x + v.y * v.y + v.z * v.z + v.w * v.w;
    #pragma unroll
    for (int off = 32; off > 0; off >>= 1) {
        sum += __shfl_xor(sum, off);
        sq  += __shfl_xor(sq, off);
    }
    __shared__ float ssum[4], ssq[4];
    const int wave = tid >> 6, lane = tid & 63;
    if (lane == 0) { ssum[wave] = sum; ssq[wave] = sq; }
    __syncthreads();
    sum = ssum[0] + ssum[1] + ssum[2] + ssum[3];
    sq  = ssq[0]  + ssq[1]  + ssq[2]  + ssq[3];
    const float mu  = sum * (1.0f / D_MODEL);
    const float var = sq * (1.0f / D_MODEL) - mu * mu;
    const float rs  = rsqrtf(var + 1e-5f);
    const float4 s4 = *(const float4*)(sc + c);
    const float4 b4 = *(const float4*)(bi + c);
    bf16x4v ov;
    ov[0] = (__bf16)((v.x - mu) * rs * s4.x + b4.x);
    ov[1] = (__bf16)((v.y - mu) * rs * s4.y + b4.y);
    ov[2] = (__bf16)((v.z - mu) * rs * s4.z + b4.z);
    ov[3] = (__bf16)((v.w - mu) * rs * s4.w + b4.w);
    *(bf16x4v*)(o + (size_t)row * D_MODEL + c) = ov;
}

// ---------------------------------------------------------------------------
// Fused per-layer weight prep: 6 transposes (f32 [K][N] -> bf16 [N][K])
// + qkv bias concat in ONE dispatch.
// ---------------------------------------------------------------------------
__global__ __launch_bounds__(256) void prep_layer_kernel(
    const float* __restrict__ wq, const float* __restrict__ wk,
    const float* __restrict__ wv, const float* __restrict__ wo,
    const float* __restrict__ w1, const float* __restrict__ w2,
    const float* __restrict__ bq, const float* __restrict__ bk,
    const float* __restrict__ bv,
    __bf16* __restrict__ wqkvT, __bf16* __restrict__ woT,
    __bf16* __restrict__ w1T, __bf16* __restrict__ w2T,
    float* __restrict__ bqkv)
{
    __shared__ __bf16 tile[32][36];
    const int b   = blockIdx.x;
    const int tid = threadIdx.x;

    if (b >= 12288) {
        const int j = (b - 12288) * 256 + tid;
        bqkv[j] = (j < 1024) ? bq[j] : (j < 2048 ? bk[j - 1024] : bv[j - 2048]);
        return;
    }

    const float* in;
    __bf16* out;
    int K, N, kb0, nb0;
    if (b < 4096) {
        const int w = b >> 10, t = b & 1023;
        K = 1024; N = 1024; kb0 = (t >> 5) * 32; nb0 = (t & 31) * 32;
        in  = (w == 0) ? wq : (w == 1) ? wk : (w == 2) ? wv : wo;
        out = (w == 3) ? woT : wqkvT + (size_t)w * 1024 * 1024;
    } else if (b < 8192) {
        const int t = b - 4096;
        K = 1024; N = 4096; kb0 = (t >> 7) * 32; nb0 = (t & 127) * 32;
        in = w1; out = w1T;
    } else {
        const int t = b - 8192;
        K = 4096; N = 1024; kb0 = (t >> 5) * 32; nb0 = (t & 31) * 32;
        in = w2; out = w2T;
    }

    {
        const int rr = tid >> 3, c4 = (tid & 7) * 4;
        const float4 v = *(const float4*)(in + (size_t)(kb0 + rr) * N + nb0 + c4);
        tile[rr][c4 + 0] = (__bf16)v.x;
        tile[rr][c4 + 1] = (__bf16)v.y;
        tile[rr][c4 + 2] = (__bf16)v.z;
        tile[rr][c4 + 3] = (__bf16)v.w;
    }
    __syncthreads();
    {
        const int cc = tid >> 3, r4 = (tid & 7) * 4;
        bf16x4v ov;
        ov[0] = tile[r4 + 0][cc];
        ov[1] = tile[r4 + 1][cc];
        ov[2] = tile[r4 + 2][cc];
        ov[3] = tile[r4 + 3][cc];
        *(bf16x4v*)(out + (size_t)(nb0 + cc) * K + kb0 + r4) = ov;
    }
}

// ---------------------------------------------------------------------------
// w_out transpose: f32 [1024][32000] -> bf16 [32000][1024].
// ---------------------------------------------------------------------------
__global__ __launch_bounds__(256) void wout_tr_kernel(
    const float* __restrict__ in, __bf16* __restrict__ out)
{
    __shared__ __bf16 tile[32][36];
    const int tid = threadIdx.x;
    const int nb0 = (blockIdx.x >> 5) * 32;
    const int kb0 = (blockIdx.x & 31) * 32;
    {
        const int rr = tid >> 3, c4 = (tid & 7) * 4;
        const float4 v = *(const float4*)(in + (size_t)(kb0 + rr) * VOCAB + nb0 + c4);
        tile[rr][c4 + 0] = (__bf16)v.x;
        tile[rr][c4 + 1] = (__bf16)v.y;
        tile[rr][c4 + 2] = (__bf16)v.z;
        tile[rr][c4 + 3] = (__bf16)v.w;
    }
    __syncthreads();
    {
        const int cc = tid >> 3, r4 = (tid & 7) * 4;
        bf16x4v ov;
        ov[0] = tile[r4 + 0][cc];
        ov[1] = tile[r4 + 1][cc];
        ov[2] = tile[r4 + 2][cc];
        ov[3] = tile[r4 + 3][cc];
        *(bf16x4v*)(out + (size_t)(nb0 + cc) * D_MODEL + kb0 + r4) = ov;
    }
}

// ---------------------------------------------------------------------------
// GEMM: C[M,N] = epi(A[M,K] @ Bt[N,K]^T + bias). bf16 in, f32 acc.
// 128 x BN_T tile, BK=64, DOUBLE-BUFFERED global_load_lds staging:
// next K-tile's loads are issued before computing the current tile, one
// __syncthreads per K-step (drain = load-complete + LDS-consumed point).
// Linear LDS dest + inverse-swizzled source + swizzled read (rule #21).
// M-fast grid + XCD chunking for B-panel L2 reuse.
// ---------------------------------------------------------------------------
template <int BN_T, int EPI, typename OutT>
__global__ __launch_bounds__(256) void gemm_bt(
    const __bf16* __restrict__ A, const __bf16* __restrict__ Bt,
    const float* __restrict__ bias, const float* __restrict__ res,
    OutT* __restrict__ C, int M, int N, int K)
{
    constexpr int NF  = BN_T / 32;      // N fragments per wave (4 or 2)
    constexpr int NCB = BN_T / 8;       // B 1KB-chunks (16 or 8)
    __shared__ __bf16 As[2][128 * 64];
    __shared__ __bf16 Bs[2][BN_T * 64];

    const int tid  = threadIdx.x;
    const int wave = tid >> 6;
    const int lane = tid & 63;
    const int r    = lane & 15;
    const int kb   = lane >> 4;
    const int wm   = wave >> 1;
    const int wn   = wave & 1;

    const int ntm = gridDim.x;                     // M/128 (fast axis)
    const int nwg = ntm * gridDim.y;
    int bid = blockIdx.y * ntm + blockIdx.x;
    if ((nwg & 7) == 0) bid = (bid & 7) * (nwg >> 3) + (bid >> 3);
    const int bm = (bid % ntm) * 128;
    const int bn = (bid / ntm) * BN_T;

    const int srow = lane >> 3;         // 0..7 within 8-row chunk
    const int sg   = lane & 7;          // granule 0..7

    f32x4 acc[4][NF] = {};

    auto stage = [&](int buf, int k0) {
        #pragma unroll
        for (int i = 0; i < 4; ++i) {               // A: 16 chunks of 1KB
            const int c    = i * 4 + wave;
            const int row  = c * 8 + srow;
            const int scol = (sg ^ (row & 7)) * 8;
            gload_lds16(A + (size_t)(bm + row) * K + k0 + scol, &As[buf][c * 512]);
        }
        #pragma unroll
        for (int i = 0; i < NCB / 4; ++i) {         // B: NCB chunks
            const int c    = i * 4 + wave;
            const int row  = c * 8 + srow;
            const int scol = (sg ^ (row & 7)) * 8;
            gload_lds16(Bt + (size_t)(bn + row) * K + k0 + scol, &Bs[buf][c * 512]);
        }
    };

    stage(0, 0);
    __syncthreads();

    int cur = 0;
    for (int k0 = 0; k0 < K; k0 += 64) {
        if (k0 + 64 < K) stage(cur ^ 1, k0 + 64);   // in flight during MFMA
        #pragma unroll
        for (int s = 0; s < 2; ++s) {
            bf16x8 af[4];
            #pragma unroll
            for (int m = 0; m < 4; ++m) {
                const int row = wm * 64 + m * 16 + r;
                const int g   = (s * 4 + kb) ^ (row & 7);
                af[m] = *(const bf16x8*)&As[cur][row * 64 + g * 8];
            }
            #pragma unroll
            for (int n = 0; n < NF; ++n) {
                const int row = wn * (NF * 16) + n * 16 + r;
                const int g   = (s * 4 + kb) ^ (row & 7);
                const bf16x8 bfr = *(const bf16x8*)&Bs[cur][row * 64 + g * 8];
                #pragma unroll
                for (int m = 0; m < 4; ++m)
                    acc[m][n] = __builtin_amdgcn_mfma_f32_16x16x32_bf16(af[m], bfr, acc[m][n], 0, 0, 0);
            }
        }
        __syncthreads();
        cur ^= 1;
    }

    #pragma unroll
    for (int m = 0; m < 4; ++m) {
        const int row = bm + wm * 64 + m * 16 + kb * 4;
        #pragma unroll
        for (int n = 0; n < NF; ++n) {
            const int col = bn + wn * (NF * 16) + n * 16 + r;
            const float bv = bias ? bias[col] : 0.0f;
            #pragma unroll
            for (int rg = 0; rg < 4; ++rg) {
                float v = acc[m][n][rg] + bv;
                if constexpr (EPI == 1) v += res[(size_t)(row + rg) * N + col];
                if constexpr (EPI == 2) v = gelu_f(v);
                C[(size_t)(row + rg) * N + col] = (OutT)v;
            }
        }
    }
}

// ---------------------------------------------------------------------------
// MFMA flash attention (causal), bf16 packed qkv (row stride 3072), bf16 out.
// One block = (b,h,64-query tile); 4 waves x 16 queries; KV tiles of 64.
// QK^T: 8 MFMAs; PV: 8 MFMAs per tile. Online softmax, 16-lane-group reduce.
// ---------------------------------------------------------------------------
__global__ __launch_bounds__(256) void attn_mfma_kernel(
    const __bf16* __restrict__ qkv, __bf16* __restrict__ y)
{
    constexpr int QS = 3 * D_MODEL;
    __shared__ __align__(16) __bf16 K_lds[64][72];
    __shared__ __align__(16) __bf16 V_lds[64][72];   // [dim][key]
    __shared__ __align__(16) __bf16 P_lds[4][16][72];

    const int tid  = threadIdx.x;
    const int wave = tid >> 6;
    const int lane = tid & 63;
    const int r    = lane & 15;
    const int kb   = lane >> 4;

    const int q0 = blockIdx.x * 64;
    const int b  = blockIdx.y >> 4;
    const int h  = blockIdx.y & 15;

    const __bf16* qp = qkv + (size_t)b * SEQ_T * QS + h * DKH;
    const __bf16* kp = qp + D_MODEL;
    const __bf16* vp = qp + 2 * D_MODEL;
    __bf16* yp = y + (size_t)b * SEQ_T * D_MODEL + h * DKH;

    bf16x8 qf[2];
    {
        const int qrow = q0 + wave * 16 + r;
        #pragma unroll
        for (int kc = 0; kc < 2; ++kc)
            qf[kc] = *(const bf16x8*)(qp + (size_t)qrow * QS + kc * 32 + kb * 8);
    }

    float m_run[4] = {-INFINITY, -INFINITY, -INFINITY, -INFINITY};
    float l_run[4] = {0.0f, 0.0f, 0.0f, 0.0f};
    f32x4 yacc[4] = {};

    const int skey = tid >> 2;          // 0..63
    const int sg   = (tid & 3) * 16;    // 0,16,32,48

    const int ntiles = blockIdx.x + 1;
    for (int kt = 0; kt < ntiles; ++kt) {
        {
            const size_t go = (size_t)(kt * 64 + skey) * QS;
            *(bf16x8*)&K_lds[skey][sg]     = *(const bf16x8*)(kp + go + sg);
            *(bf16x8*)&K_lds[skey][sg + 8] = *(const bf16x8*)(kp + go + sg + 8);
            const bf16x8 v0 = *(const bf16x8*)(vp + go + sg);
            const bf16x8 v1 = *(const bf16x8*)(vp + go + sg + 8);
            #pragma unroll
            for (int j = 0; j < 8; ++j) V_lds[sg + j][skey]     = v0[j];
            #pragma unroll
            for (int j = 0; j < 8; ++j) V_lds[sg + 8 + j][skey] = v1[j];
        }
        __syncthreads();

        f32x4 sacc[4] = {};
        #pragma unroll
        for (int kc = 0; kc < 2; ++kc) {
            #pragma unroll
            for (int g = 0; g < 4; ++g) {
                const bf16x8 kf = *(const bf16x8*)&K_lds[g * 16 + r][kc * 32 + kb * 8];
                sacc[g] = __builtin_amdgcn_mfma_f32_16x16x32_bf16(qf[kc], kf, sacc[g], 0, 0, 0);
            }
        }

        float s[4][4], p[4][4];
        #pragma unroll
        for (int g = 0; g < 4; ++g) {
            const int key = kt * 64 + g * 16 + r;
            #pragma unroll
            for (int rg = 0; rg < 4; ++rg) {
                const int qq = q0 + wave * 16 + kb * 4 + rg;
                s[g][rg] = (key <= qq) ? sacc[g][rg] * 0.125f : -INFINITY;
            }
        }
        float mt[4], mn[4], corr[4], psum[4];
        #pragma unroll
        for (int rg = 0; rg < 4; ++rg)
            mt[rg] = fmaxf(fmaxf(s[0][rg], s[1][rg]), fmaxf(s[2][rg], s[3][rg]));
        #pragma unroll
        for (int off = 1; off < 16; off <<= 1) {
            #pragma unroll
            for (int rg = 0; rg < 4; ++rg) mt[rg] = fmaxf(mt[rg], __shfl_xor(mt[rg], off));
        }
        #pragma unroll
        for (int rg = 0; rg < 4; ++rg) {
            mn[rg]  = fmaxf(m_run[rg], mt[rg]);
            psum[rg] = 0.0f;
            #pragma unroll
            for (int g = 0; g < 4; ++g) {
                p[g][rg] = __expf(s[g][rg] - mn[rg]);
                psum[rg] += p[g][rg];
            }
        }
        #pragma unroll
        for (int off = 1; off < 16; off <<= 1) {
            #pragma unroll
            for (int rg = 0; rg < 4; ++rg) psum[rg] += __shfl_xor(psum[rg], off);
        }
        #pragma unroll
        for (int rg = 0; rg < 4; ++rg) {
            corr[rg] = __expf(m_run[rg] - mn[rg]);
            l_run[rg] = l_run[rg] * corr[rg] + psum[rg];
            m_run[rg] = mn[rg];
        }
        #pragma unroll
        for (int n = 0; n < 4; ++n) {
            #pragma unroll
            for (int rg = 0; rg < 4; ++rg) yacc[n][rg] *= corr[rg];
        }

        #pragma unroll
        for (int g = 0; g < 4; ++g) {
            #pragma unroll
            for (int rg = 0; rg < 4; ++rg)
                P_lds[wave][kb * 4 + rg][g * 16 + r] = (__bf16)p[g][rg];
        }
        const bf16x8 pa0 = *(const bf16x8*)&P_lds[wave][r][kb * 8];
        const bf16x8 pa1 = *(const bf16x8*)&P_lds[wave][r][32 + kb * 8];

        #pragma unroll
        for (int n = 0; n < 4; ++n) {
            const bf16x8 vf0 = *(const bf16x8*)&V_lds[n * 16 + r][kb * 8];
            yacc[n] = __builtin_amdgcn_mfma_f32_16x16x32_bf16(pa0, vf0, yacc[n], 0, 0, 0);
        }
        #pragma unroll
        for (int n = 0; n < 4; ++n) {
            const bf16x8 vf1 = *(const bf16x8*)&V_lds[n * 16 + r][32 + kb * 8];
            yacc[n] = __builtin_amdgcn_mfma_f32_16x16x32_bf16(pa1, vf1, yacc[n], 0, 0, 0);
        }
        __syncthreads();
    }

    float inv[4];
    #pragma unroll
    for (int rg = 0; rg < 4; ++rg) inv[rg] = 1.0f / l_run[rg];
    #pragma unroll
    for (int n = 0; n < 4; ++n) {
        #pragma unroll
        for (int rg = 0; rg < 4; ++rg) {
            const int row = q0 + wave * 16 + kb * 4 + rg;
            yp[(size_t)row * D_MODEL + n * 16 + r] = (__bf16)(yacc[n][rg] * inv[rg]);
        }
    }
}

// ---------------------------------------------------------------------------
extern "C" void kernel_launch(void* const* d_in, const int* in_sizes, int n_in,
                              void* d_out, int out_size, void* d_ws, size_t ws_size,
                              hipStream_t stream)
{
    const int*   x       = (const int*)  d_in[0];
    const float* inp_emb = (const float*)d_in[1];
    const float* pos_emb = (const float*)d_in[2];
    const float* wq = (const float*)d_in[3];
    const float* bq = (const float*)d_in[4];
    const float* wk = (const float*)d_in[5];
    const float* bk = (const float*)d_in[6];
    const float* wv = (const float*)d_in[7];
    const float* bv = (const float*)d_in[8];
    const float* wo = (const float*)d_in[9];
    const float* bo = (const float*)d_in[10];
    const float* w1 = (const float*)d_in[11];
    const float* b1 = (const float*)d_in[12];
    const float* w2 = (const float*)d_in[13];
    const float* b2 = (const float*)d_in[14];
    const float* ln1_s = (const float*)d_in[15];
    const float* ln1_b = (const float*)d_in[16];
    const float* ln2_s = (const float*)d_in[17];
    const float* ln2_b = (const float*)d_in[18];
    const float* lno_s = (const float*)d_in[19];
    const float* lno_b = (const float*)d_in[20];
    const float* w_out = (const float*)d_in[21];

    const int M = BATCH * SEQ_T;                 // 2048
    const size_t MB = 1u << 20;

    char* w = (char*)d_ws;
    float*  h     = (float*) (w + 0);            // 8MB
    __bf16* xn    = (__bf16*)(w + 8  * MB);      // 4MB
    __bf16* yb    = (__bf16*)(w + 12 * MB);      // 4MB
    __bf16* sh    = (__bf16*)(w + 16 * MB);      // qkv/mid 16MB
    __bf16* wqkvT = (__bf16*)(w + 32 * MB);      // 6MB
    __bf16* woT   = (__bf16*)(w + 38 * MB);      // 2MB
    __bf16* w1T   = (__bf16*)(w + 40 * MB);      // 8MB
    __bf16* w2T   = (__bf16*)(w + 48 * MB);      // 8MB
    float*  bqkv  = (float*) (w + 56 * MB);      // 12KB
    __bf16* woutT = (__bf16*)(w + 57 * MB);      // 62.5MB

    embed_kernel<<<dim3(M * D_MODEL / 256), 256, 0, stream>>>(x, inp_emb, pos_emb, h);

    for (int i = 0; i < NLAYERS; ++i) {
        const size_t wOff  = (size_t)i * D_MODEL * D_MODEL;
        const size_t w1Off = (size_t)i * D_MODEL * DFF_;

        prep_layer_kernel<<<dim3(12300), 256, 0, stream>>>(
            wq + wOff, wk + wOff, wv + wOff, wo + wOff, w1 + w1Off, w2 + w1Off,
            bq + i * D_MODEL, bk + i * D_MODEL, bv + i * D_MODEL,
            wqkvT, woT, w1T, w2T, bqkv);

        layernorm_kernel<<<dim3(M), 256, 0, stream>>>(h, ln1_s + i * D_MODEL, ln1_b + i * D_MODEL, xn);
        gemm_bt<128, 0, __bf16><<<dim3(M / 128, 3 * D_MODEL / 128), 256, 0, stream>>>(
            xn, wqkvT, bqkv, nullptr, sh, M, 3 * D_MODEL, D_MODEL);
        attn_mfma_kernel<<<dim3(SEQ_T / 64, BATCH * N_HEADS), 256, 0, stream>>>(sh, yb);
        gemm_bt<64, 1, float><<<dim3(M / 128, D_MODEL / 64), 256, 0, stream>>>(
            yb, woT, bo + i * D_MODEL, h, h, M, D_MODEL, D_MODEL);
        layernorm_kernel<<<dim3(M), 256, 0, stream>>>(h, ln2_s + i * D_MODEL, ln2_b + i * D_MODEL, xn);
        gemm_bt<128, 2, __bf16><<<dim3(M / 128, DFF_ / 128), 256, 0, stream>>>(
            xn, w1T, b1 + i * DFF_, nullptr, sh, M, DFF_, D_MODEL);
        gemm_bt<64, 1, float><<<dim3(M / 128, D_MODEL / 64), 256, 0, stream>>>(
            sh, w2T, b2 + i * D_MODEL, h, h, M, D_MODEL, DFF_);
    }

    wout_tr_kernel<<<dim3((VOCAB / 32) * 32), 256, 0, stream>>>(w_out, woutT);
    layernorm_kernel<<<dim3(M), 256, 0, stream>>>(h, lno_s, lno_b, xn);
    gemm_bt<128, 0, float><<<dim3(M / 128, VOCAB / 128), 256, 0, stream>>>(
        xn, woutT, nullptr, nullptr, (float*)d_out, M, VOCAB, D_MODEL);
}